// Round 1
// baseline (2421.562 us; speedup 1.0000x reference)
//
#include <hip/hip_runtime.h>
#include <hip/hip_bf16.h>
#include <math.h>

typedef __attribute__((ext_vector_type(8))) short short8;
typedef __attribute__((ext_vector_type(4))) float f32x4;
typedef __attribute__((ext_vector_type(4))) int int4v;

#define NH 12
#define DIM 384
#define HD 32

__device__ inline f32x4 mfma16(short8 a, short8 b, f32x4 c){
  return __builtin_amdgcn_mfma_f32_16x16x32_bf16(a, b, c, 0, 0, 0);
}

__device__ inline short fbits(float f){
  __hip_bfloat16 h = __float2bfloat16(f);
  short s; __builtin_memcpy(&s, &h, 2); return s;
}

__device__ inline float wsum16(float v){
  #pragma unroll
  for (int off = 1; off < 16; off <<= 1) v += __shfl_xor(v, off);
  return v;
}
__device__ inline float wmax16(float v){
  #pragma unroll
  for (int off = 1; off < 16; off <<= 1) v = fmaxf(v, __shfl_xor(v, off));
  return v;
}

__global__ void k_f32_to_bf16(const float* __restrict__ src,
                              __hip_bfloat16* __restrict__ dst, int n){
  int i = blockIdx.x * blockDim.x + threadIdx.x;
  int stride = gridDim.x * blockDim.x;
  for (; i < n; i += stride) dst[i] = __float2bfloat16(src[i]);
}

__device__ inline float cpbf(int a){
  float v = (float)a * (8.0f / 7.0f);
  float s = (v > 0.f) ? 1.f : ((v < 0.f) ? -1.f : 0.f);
  return s * log2f(fabsf(v) + 1.0f) * (1.0f / 3.0f);
}

__global__ __launch_bounds__(256) void k_cpb(
    const float* __restrict__ w1, const float* __restrict__ b1,
    const float* __restrict__ w2, float* __restrict__ hbias)
{
  __shared__ float hid[512];
  int t = blockIdx.x;  // 0..224
  float t0 = cpbf(t / 15 - 7), t1 = cpbf(t % 15 - 7);
  for (int j = threadIdx.x; j < 512; j += 256)
    hid[j] = fmaxf(w1[j * 2 + 0] * t0 + w1[j * 2 + 1] * t1 + b1[j], 0.f);
  __syncthreads();
  if (threadIdx.x < NH){
    float s = 0.f;
    for (int j = 0; j < 512; j++) s += hid[j] * w2[threadIdx.x * 512 + j];
    hbias[t * NH + threadIdx.x] = s;
  }
}

__global__ void k_bias16(const float* __restrict__ hbias,
                         const float* __restrict__ logit_scale,
                         float* __restrict__ bias16, float* __restrict__ scalev)
{
  int i = blockIdx.x * blockDim.x + threadIdx.x;
  if (i < NH) scalev[i] = expf(fminf(logit_scale[i], logf(100.0f)));
  if (i >= NH * 64 * 64) return;
  int h = i >> 12, r = (i >> 6) & 63, c = i & 63;
  int t = ((r >> 3) - (c >> 3) + 7) * 15 + ((r & 7) - (c & 7) + 7);
  float b = hbias[t * NH + h];
  bias16[i] = 16.0f / (1.0f + expf(-b));
}

// ---------------- attention: one workgroup per 8x8 window ----------------
__global__ __launch_bounds__(256, 1) void k_attn(
    const float* __restrict__ x,
    const __hip_bfloat16* __restrict__ qkvw,
    const float* __restrict__ qkvb,
    const float* __restrict__ scalev,
    const float* __restrict__ bias16,
    __hip_bfloat16* __restrict__ attnout)
{
  __shared__ __hip_bfloat16 wbuf[192][40];   // weight k-chunk
  __shared__ __hip_bfloat16 qk[4][64][40];   // q0,q1,k0,k1
  __shared__ __hip_bfloat16 vT[2][32][72];   // v transposed [d][token]
  __shared__ __hip_bfloat16 Pb[2][64][72];   // softmax P
  __shared__ int lblS[64];

  const int tid = threadIdx.x;
  const int lane = tid & 63;
  const int wid = tid >> 6;
  const int wi = blockIdx.x;
  const int bb = wi >> 6, wh = (wi >> 3) & 7, ww = wi & 7;

  if (tid < 64){
    int rr = tid >> 3, cc = tid & 7;
    int hs = wh * 8 + rr, ws2 = ww * 8 + cc;
    int rh = (hs < 56) ? 0 : (hs < 60 ? 1 : 2);
    int rw = (ws2 < 56) ? 0 : (ws2 < 60 ? 1 : 2);
    lblS[tid] = rh * 3 + rw;
  }

  // A fragments (window tokens) in registers; reused for q,k,v GEMMs
  short8 afr[12];
  {
    int t = wid * 16 + (lane & 15);
    int rr = t >> 3, cc = t & 7;
    int h = (wh * 8 + rr + 4) & 63, w = (ww * 8 + cc + 4) & 63;
    const float4* p = (const float4*)(x + ((size_t)((bb << 12) + (h << 6) + w)) * DIM);
    int kb4 = (lane >> 4) * 2;
    #pragma unroll
    for (int kc = 0; kc < 12; kc++){
      float4 f0 = p[kc * 8 + kb4];
      float4 f1 = p[kc * 8 + kb4 + 1];
      short8 s;
      s[0] = fbits(f0.x); s[1] = fbits(f0.y); s[2] = fbits(f0.z); s[3] = fbits(f0.w);
      s[4] = fbits(f1.x); s[5] = fbits(f1.y); s[6] = fbits(f1.z); s[7] = fbits(f1.w);
      afr[kc] = s;
    }
  }

  const int kb = (lane >> 4) * 8;
  const int colb = lane & 15;
  const int rbase = wid * 16 + ((lane >> 4) << 2);

  for (int hg = 0; hg < 6; hg++){   // 2 heads per group
    f32x4 acc[12];
    #pragma unroll
    for (int n = 0; n < 12; n++) acc[n] = (f32x4)(0.f);

    for (int kc = 0; kc < 12; kc++){
      __syncthreads();
      #pragma unroll
      for (int u = tid; u < 768; u += 256){
        int row = u >> 2, cg = u & 3;
        int grow = (row >> 6) * DIM + hg * 64 + (row & 63);
        *(int4v*)&wbuf[row][cg * 8] =
            *(const int4v*)(qkvw + (size_t)grow * DIM + kc * 32 + cg * 8);
      }
      __syncthreads();
      #pragma unroll
      for (int n = 0; n < 12; n++){
        short8 bfr = *(const short8*)&wbuf[n * 16 + colb][kb];
        acc[n] = mfma16(afr[kc], bfr, acc[n]);
      }
    }

    // scatter to q/k (raw) and vT (+bias)
    #pragma unroll
    for (int n = 0; n < 12; n++){
      int c = n * 16 + colb;     // 0..191
      int seg = c >> 6;          // 0=q 1=k 2=v
      int cl = c & 63;
      int hh = cl >> 5, d = cl & 31;
      float bias = qkvb[seg * DIM + hg * 64 + cl];
      if (seg < 2){
        #pragma unroll
        for (int r = 0; r < 4; r++)
          qk[seg * 2 + hh][rbase + r][d] = __float2bfloat16(acc[n][r] + bias);
      } else {
        #pragma unroll
        for (int r = 0; r < 4; r++)
          vT[hh][d][rbase + r] = __float2bfloat16(acc[n][r] + bias);
      }
    }
    __syncthreads();

    // cosine-normalize q,k rows: 256 threads = 4 arrays x 64 rows
    {
      int a = tid >> 6, r = tid & 63;
      float s = 0.f;
      #pragma unroll
      for (int d = 0; d < 32; d++){
        float v = __bfloat162float(qk[a][r][d]); s += v * v;
      }
      float inv = 1.0f / fmaxf(sqrtf(s), 1e-12f);
      #pragma unroll
      for (int d = 0; d < 32; d++)
        qk[a][r][d] = __float2bfloat16(__bfloat162float(qk[a][r][d]) * inv);
    }
    __syncthreads();

    // attention: wave -> (head hh, row-half mh)
    {
      const int hh = wid & 1, mh = wid >> 1;
      const int head = hg * 2 + hh;
      const float sc = scalev[head];
      f32x4 sacc[2][4];
      #pragma unroll
      for (int mi = 0; mi < 2; mi++)
        #pragma unroll
        for (int ni = 0; ni < 4; ni++) sacc[mi][ni] = (f32x4)(0.f);
      short8 qf[2];
      #pragma unroll
      for (int mi = 0; mi < 2; mi++)
        qf[mi] = *(const short8*)&qk[hh][mh * 32 + mi * 16 + colb][kb];
      #pragma unroll
      for (int ni = 0; ni < 4; ni++){
        short8 kf = *(const short8*)&qk[2 + hh][ni * 16 + colb][kb];
        #pragma unroll
        for (int mi = 0; mi < 2; mi++)
          sacc[mi][ni] = mfma16(qf[mi], kf, sacc[mi][ni]);
      }
      const float* bptr = bias16 + (size_t)head * 4096;
      #pragma unroll
      for (int mi = 0; mi < 2; mi++){
        int rb = mh * 32 + mi * 16 + ((lane >> 4) << 2);
        #pragma unroll
        for (int r = 0; r < 4; r++){
          int rm = rb + r;
          int li = lblS[rm];
          float v[4]; float mx = -1e30f;
          #pragma unroll
          for (int ni = 0; ni < 4; ni++){
            int cn = ni * 16 + colb;
            float t = sacc[mi][ni][r] * sc + bptr[rm * 64 + cn]
                      + ((lblS[cn] == li) ? 0.f : -100.f);
            v[ni] = t; mx = fmaxf(mx, t);
          }
          mx = wmax16(mx);
          float s = 0.f;
          #pragma unroll
          for (int ni = 0; ni < 4; ni++){ v[ni] = __expf(v[ni] - mx); s += v[ni]; }
          s = wsum16(s);
          float is = 1.0f / s;
          #pragma unroll
          for (int ni = 0; ni < 4; ni++)
            Pb[hh][rm][ni * 16 + colb] = __float2bfloat16(v[ni] * is);
        }
      }
      __syncthreads();
      f32x4 oacc[2][2];
      #pragma unroll
      for (int mi = 0; mi < 2; mi++)
        #pragma unroll
        for (int ni = 0; ni < 2; ni++) oacc[mi][ni] = (f32x4)(0.f);
      #pragma unroll
      for (int kc2 = 0; kc2 < 2; kc2++){
        short8 pf[2];
        #pragma unroll
        for (int mi = 0; mi < 2; mi++)
          pf[mi] = *(const short8*)&Pb[hh][mh * 32 + mi * 16 + colb][kc2 * 32 + kb];
        #pragma unroll
        for (int ni = 0; ni < 2; ni++){
          short8 vf = *(const short8*)&vT[hh][ni * 16 + colb][kc2 * 32 + kb];
          #pragma unroll
          for (int mi = 0; mi < 2; mi++)
            oacc[mi][ni] = mfma16(pf[mi], vf, oacc[mi][ni]);
        }
      }
      #pragma unroll
      for (int mi = 0; mi < 2; mi++)
        #pragma unroll
        for (int ni = 0; ni < 2; ni++)
          #pragma unroll
          for (int r = 0; r < 4; r++){
            int rm = mh * 32 + mi * 16 + ((lane >> 4) << 2) + r;
            int c = head * HD + ni * 16 + colb;
            attnout[((size_t)wi * 64 + rm) * DIM + c] = __float2bfloat16(oacc[mi][ni][r]);
          }
    }
    __syncthreads();
  }
}

// ---------------- proj + unwindow/unshift + residual + LN1 ----------------
__global__ __launch_bounds__(256, 1) void k_proj(
    const __hip_bfloat16* __restrict__ attnout,
    const __hip_bfloat16* __restrict__ projw,
    const float* __restrict__ projb,
    const float* __restrict__ x,
    const float* __restrict__ g1, const float* __restrict__ b1v,
    __hip_bfloat16* __restrict__ y)
{
  __shared__ __hip_bfloat16 wbuf[384][40];
  const int tid = threadIdx.x, lane = tid & 63, wid = tid >> 6;
  const int wi = blockIdx.x;
  const int kb = (lane >> 4) * 8, colb = lane & 15;
  const int rbase = wid * 16 + ((lane >> 4) << 2);

  short8 afr[12];
  {
    const __hip_bfloat16* ap = attnout + ((size_t)wi * 64 + wid * 16 + colb) * DIM;
    #pragma unroll
    for (int kc = 0; kc < 12; kc++)
      afr[kc] = *(const short8*)(ap + kc * 32 + kb);
  }

  f32x4 acc[24];
  #pragma unroll
  for (int n = 0; n < 24; n++) acc[n] = (f32x4)(0.f);

  for (int kc = 0; kc < 12; kc++){
    __syncthreads();
    #pragma unroll
    for (int u = tid; u < 1536; u += 256){
      int row = u >> 2, cg = u & 3;
      *(int4v*)&wbuf[row][cg * 8] =
          *(const int4v*)(projw + (size_t)row * DIM + kc * 32 + cg * 8);
    }
    __syncthreads();
    #pragma unroll
    for (int n = 0; n < 24; n++){
      short8 bfr = *(const short8*)&wbuf[n * 16 + colb][kb];
      acc[n] = mfma16(afr[kc], bfr, acc[n]);
    }
  }

  float s1[4] = {0,0,0,0}, s2[4] = {0,0,0,0};
  #pragma unroll
  for (int n = 0; n < 24; n++){
    float pb = projb[n * 16 + colb];
    #pragma unroll
    for (int r = 0; r < 4; r++){
      float v = acc[n][r] + pb; acc[n][r] = v;
      s1[r] += v; s2[r] += v * v;
    }
  }
  #pragma unroll
  for (int r = 0; r < 4; r++){ s1[r] = wsum16(s1[r]); s2[r] = wsum16(s2[r]); }

  const int bb = wi >> 6, wh = (wi >> 3) & 7, ww = wi & 7;
  #pragma unroll
  for (int r = 0; r < 4; r++){
    int t = rbase + r;
    int rr = t >> 3, cc = t & 7;
    int h = (wh * 8 + rr + 4) & 63, w = (ww * 8 + cc + 4) & 63;
    size_t gpos = (size_t)(bb << 12) + (h << 6) + w;
    float mean = s1[r] * (1.f / 384.f);
    float var = s2[r] * (1.f / 384.f) - mean * mean;
    float inv = rsqrtf(var + 1e-5f);
    const float* xp = x + gpos * DIM;
    __hip_bfloat16* yp = y + gpos * DIM;
    #pragma unroll
    for (int n = 0; n < 24; n++){
      int c = n * 16 + colb;
      float ln = (acc[n][r] - mean) * inv * g1[c] + b1v[c];
      yp[c] = __float2bfloat16(xp[c] + ln);
    }
  }
}

// ---------------- fused MLP (fc1+gelu+fc2) + LN2 + residual ----------------
__global__ __launch_bounds__(256, 1) void k_mlp(
    const __hip_bfloat16* __restrict__ y,
    const __hip_bfloat16* __restrict__ fc1w, const float* __restrict__ fc1b,
    const __hip_bfloat16* __restrict__ fc2w, const float* __restrict__ fc2b,
    const float* __restrict__ g2, const float* __restrict__ b2v,
    float* __restrict__ out)
{
  __shared__ __hip_bfloat16 wbuf[384][40];   // 30720 B
  __shared__ __hip_bfloat16 hbuf[64][200];   // 25600 B
  const int tid = threadIdx.x, lane = tid & 63, wid = tid >> 6;
  const size_t row0 = (size_t)blockIdx.x * 64;
  const int kb = (lane >> 4) * 8, colb = lane & 15;
  const int rbase = wid * 16 + ((lane >> 4) << 2);

  short8 afr[12];
  {
    const __hip_bfloat16* ap = y + (row0 + wid * 16 + colb) * DIM;
    #pragma unroll
    for (int kc = 0; kc < 12; kc++)
      afr[kc] = *(const short8*)(ap + kc * 32 + kb);
  }

  f32x4 acc2[24];
  #pragma unroll
  for (int n = 0; n < 24; n++) acc2[n] = (f32x4)(0.f);

  for (int ch = 0; ch < 8; ch++){   // 192 hidden cols per chunk
    f32x4 acc1[12];
    #pragma unroll
    for (int n = 0; n < 12; n++) acc1[n] = (f32x4)(0.f);

    for (int kc = 0; kc < 12; kc++){
      __syncthreads();
      #pragma unroll
      for (int u = tid; u < 768; u += 256){
        int row = u >> 2, cg = u & 3;
        *(int4v*)&wbuf[row][cg * 8] =
            *(const int4v*)(fc1w + (size_t)(ch * 192 + row) * DIM + kc * 32 + cg * 8);
      }
      __syncthreads();
      #pragma unroll
      for (int n = 0; n < 12; n++){
        short8 bfr = *(const short8*)&wbuf[n * 16 + colb][kb];
        acc1[n] = mfma16(afr[kc], bfr, acc1[n]);
      }
    }
    __syncthreads();
    #pragma unroll
    for (int n = 0; n < 12; n++){
      float fb = fc1b[ch * 192 + n * 16 + colb];
      #pragma unroll
      for (int r = 0; r < 4; r++){
        float v = acc1[n][r] + fb;
        float gl = 0.5f * v * (1.0f + erff(v * 0.70710678118654752f));
        hbuf[rbase + r][n * 16 + colb] = __float2bfloat16(gl);
      }
    }
    __syncthreads();

    for (int kc = 0; kc < 6; kc++){
      __syncthreads();
      #pragma unroll
      for (int u = tid; u < 1536; u += 256){
        int row = u >> 2, cg = u & 3;
        *(int4v*)&wbuf[row][cg * 8] =
            *(const int4v*)(fc2w + (size_t)row * 1536 + ch * 192 + kc * 32 + cg * 8);
      }
      __syncthreads();
      short8 hf = *(const short8*)&hbuf[wid * 16 + colb][kc * 32 + kb];
      #pragma unroll
      for (int n = 0; n < 24; n++){
        short8 bfr = *(const short8*)&wbuf[n * 16 + colb][kb];
        acc2[n] = mfma16(hf, bfr, acc2[n]);
      }
    }
    __syncthreads();
  }

  float s1[4] = {0,0,0,0}, s2[4] = {0,0,0,0};
  #pragma unroll
  for (int n = 0; n < 24; n++){
    float fb = fc2b[n * 16 + colb];
    #pragma unroll
    for (int r = 0; r < 4; r++){
      float v = acc2[n][r] + fb; acc2[n][r] = v;
      s1[r] += v; s2[r] += v * v;
    }
  }
  #pragma unroll
  for (int r = 0; r < 4; r++){ s1[r] = wsum16(s1[r]); s2[r] = wsum16(s2[r]); }
  #pragma unroll
  for (int r = 0; r < 4; r++){
    size_t grow = row0 + rbase + r;
    float mean = s1[r] * (1.f / 384.f);
    float var = s2[r] * (1.f / 384.f) - mean * mean;
    float inv = rsqrtf(var + 1e-5f);
    const __hip_bfloat16* yp = y + grow * DIM;
    float* op = out + grow * DIM;
    #pragma unroll
    for (int n = 0; n < 24; n++){
      int c = n * 16 + colb;
      float ln = (acc2[n][r] - mean) * inv * g2[c] + b2v[c];
      op[c] = __bfloat162float(yp[c]) + ln;
    }
  }
}

extern "C" void kernel_launch(void* const* d_in, const int* in_sizes, int n_in,
                              void* d_out, int out_size, void* d_ws, size_t ws_size,
                              hipStream_t stream)
{
  (void)in_sizes; (void)n_in; (void)out_size; (void)ws_size;
  const float* x    = (const float*)d_in[0];
  const float* qkvw_f = (const float*)d_in[3];
  const float* qkvb = (const float*)d_in[4];
  const float* lsc  = (const float*)d_in[5];
  const float* cw1  = (const float*)d_in[6];
  const float* cb1  = (const float*)d_in[7];
  const float* cw2  = (const float*)d_in[8];
  const float* pw   = (const float*)d_in[9];
  const float* pb   = (const float*)d_in[10];
  const float* g1   = (const float*)d_in[11];
  const float* b1   = (const float*)d_in[12];
  const float* g2   = (const float*)d_in[13];
  const float* b2   = (const float*)d_in[14];
  const float* f1w  = (const float*)d_in[15];
  const float* f1b  = (const float*)d_in[16];
  const float* f2w  = (const float*)d_in[17];
  const float* f2b  = (const float*)d_in[18];

  char* ws = (char*)d_ws;
  size_t off = 0;
  auto alloc = [&](size_t bytes) -> char* {
    char* p = ws + off;
    off += (bytes + 255) & ~(size_t)255;
    return p;
  };
  __hip_bfloat16* qkvw_h  = (__hip_bfloat16*)alloc((size_t)1152 * 384 * 2);
  __hip_bfloat16* projw_h = (__hip_bfloat16*)alloc((size_t)384 * 384 * 2);
  __hip_bfloat16* fc1w_h  = (__hip_bfloat16*)alloc((size_t)1536 * 384 * 2);
  __hip_bfloat16* fc2w_h  = (__hip_bfloat16*)alloc((size_t)384 * 1536 * 2);
  float* scalev = (float*)alloc(NH * 4);
  float* hbias  = (float*)alloc(225 * NH * 4);
  float* bias16 = (float*)alloc((size_t)NH * 64 * 64 * 4);
  __hip_bfloat16* attnout = (__hip_bfloat16*)alloc((size_t)2048 * 64 * 384 * 2);
  __hip_bfloat16* yb      = (__hip_bfloat16*)alloc((size_t)131072 * 384 * 2);

  k_f32_to_bf16<<<512, 256, 0, stream>>>(qkvw_f, qkvw_h, 1152 * 384);
  k_f32_to_bf16<<<256, 256, 0, stream>>>(pw, projw_h, 384 * 384);
  k_f32_to_bf16<<<512, 256, 0, stream>>>(f1w, fc1w_h, 1536 * 384);
  k_f32_to_bf16<<<512, 256, 0, stream>>>(f2w, fc2w_h, 384 * 1536);
  k_cpb<<<225, 256, 0, stream>>>(cw1, cb1, cw2, hbias);
  k_bias16<<<192, 256, 0, stream>>>(hbias, lsc, bias16, scalev);
  k_attn<<<2048, 256, 0, stream>>>(x, qkvw_h, qkvb, scalev, bias16, attnout);
  k_proj<<<2048, 256, 0, stream>>>(attnout, projw_h, pb, x, g1, b1, yb);
  k_mlp<<<2048, 256, 0, stream>>>(yb, fc1w_h, f1b, fc2w_h, f2b, g2, b2, (float*)d_out);
}

// Round 2
// 1623.678 us; speedup vs baseline: 1.4914x; 1.4914x over previous
//
#include <hip/hip_runtime.h>
#include <hip/hip_bf16.h>
#include <math.h>

typedef __attribute__((ext_vector_type(8))) short short8;
typedef __attribute__((ext_vector_type(4))) float f32x4;
typedef __attribute__((ext_vector_type(4))) int int4v;

#define NH 12
#define DIM 384
#define HD 32

__device__ inline f32x4 mfma16(short8 a, short8 b, f32x4 c){
  return __builtin_amdgcn_mfma_f32_16x16x32_bf16(a, b, c, 0, 0, 0);
}

__device__ inline short fbits(float f){
  __hip_bfloat16 h = __float2bfloat16(f);
  short s; __builtin_memcpy(&s, &h, 2); return s;
}

__device__ inline float wsum16(float v){
  #pragma unroll
  for (int off = 1; off < 16; off <<= 1) v += __shfl_xor(v, off);
  return v;
}
__device__ inline float wmax16(float v){
  #pragma unroll
  for (int off = 1; off < 16; off <<= 1) v = fmaxf(v, __shfl_xor(v, off));
  return v;
}

__device__ inline void gload16(const void* g, void* l){
  __builtin_amdgcn_global_load_lds(
      (const __attribute__((address_space(1))) unsigned int*)g,
      (__attribute__((address_space(3))) unsigned int*)l, 16, 0, 0);
}

__global__ void k_f32_to_bf16(const float* __restrict__ src,
                              __hip_bfloat16* __restrict__ dst, int n){
  int i = blockIdx.x * blockDim.x + threadIdx.x;
  int stride = gridDim.x * blockDim.x;
  for (; i < n; i += stride) dst[i] = __float2bfloat16(src[i]);
}

__device__ inline float cpbf(int a){
  float v = (float)a * (8.0f / 7.0f);
  float s = (v > 0.f) ? 1.f : ((v < 0.f) ? -1.f : 0.f);
  return s * log2f(fabsf(v) + 1.0f) * (1.0f / 3.0f);
}

__global__ __launch_bounds__(256) void k_cpb(
    const float* __restrict__ w1, const float* __restrict__ b1,
    const float* __restrict__ w2, float* __restrict__ hbias)
{
  __shared__ float hid[512];
  int t = blockIdx.x;  // 0..224
  float t0 = cpbf(t / 15 - 7), t1 = cpbf(t % 15 - 7);
  for (int j = threadIdx.x; j < 512; j += 256)
    hid[j] = fmaxf(w1[j * 2 + 0] * t0 + w1[j * 2 + 1] * t1 + b1[j], 0.f);
  __syncthreads();
  if (threadIdx.x < NH){
    float s = 0.f;
    for (int j = 0; j < 512; j++) s += hid[j] * w2[threadIdx.x * 512 + j];
    hbias[t * NH + threadIdx.x] = s;
  }
}

__global__ void k_bias16(const float* __restrict__ hbias,
                         const float* __restrict__ logit_scale,
                         float* __restrict__ bias16, float* __restrict__ scalev)
{
  int i = blockIdx.x * blockDim.x + threadIdx.x;
  if (i < NH) scalev[i] = expf(fminf(logit_scale[i], logf(100.0f)));
  if (i >= NH * 64 * 64) return;
  int h = i >> 12, r = (i >> 6) & 63, c = i & 63;
  int t = ((r >> 3) - (c >> 3) + 7) * 15 + ((r & 7) - (c & 7) + 7);
  float b = hbias[t * NH + h];
  bias16[i] = 16.0f / (1.0f + expf(-b));
}

// ---------------- attention: one workgroup per 8x8 window ----------------
__global__ __launch_bounds__(256, 1) void k_attn(
    const float* __restrict__ x,
    const __hip_bfloat16* __restrict__ qkvw,
    const float* __restrict__ qkvb,
    const float* __restrict__ scalev,
    const float* __restrict__ bias16,
    __hip_bfloat16* __restrict__ attnout)
{
  __shared__ __hip_bfloat16 wbuf[192][40];   // weight k-chunk
  __shared__ __hip_bfloat16 qk[4][64][40];   // q0,q1,k0,k1
  __shared__ __hip_bfloat16 vT[2][32][72];   // v transposed [d][token]
  __shared__ __hip_bfloat16 Pb[2][64][72];   // softmax P
  __shared__ int lblS[64];

  const int tid = threadIdx.x;
  const int lane = tid & 63;
  const int wid = tid >> 6;
  const int wi = blockIdx.x;
  const int bb = wi >> 6, wh = (wi >> 3) & 7, ww = wi & 7;

  if (tid < 64){
    int rr = tid >> 3, cc = tid & 7;
    int hs = wh * 8 + rr, ws2 = ww * 8 + cc;
    int rh = (hs < 56) ? 0 : (hs < 60 ? 1 : 2);
    int rw = (ws2 < 56) ? 0 : (ws2 < 60 ? 1 : 2);
    lblS[tid] = rh * 3 + rw;
  }

  // A fragments (window tokens) in registers; reused for q,k,v GEMMs
  short8 afr[12];
  {
    int t = wid * 16 + (lane & 15);
    int rr = t >> 3, cc = t & 7;
    int h = (wh * 8 + rr + 4) & 63, w = (ww * 8 + cc + 4) & 63;
    const float4* p = (const float4*)(x + ((size_t)((bb << 12) + (h << 6) + w)) * DIM);
    int kb4 = (lane >> 4) * 2;
    #pragma unroll
    for (int kc = 0; kc < 12; kc++){
      float4 f0 = p[kc * 8 + kb4];
      float4 f1 = p[kc * 8 + kb4 + 1];
      short8 s;
      s[0] = fbits(f0.x); s[1] = fbits(f0.y); s[2] = fbits(f0.z); s[3] = fbits(f0.w);
      s[4] = fbits(f1.x); s[5] = fbits(f1.y); s[6] = fbits(f1.z); s[7] = fbits(f1.w);
      afr[kc] = s;
    }
  }

  const int kb = (lane >> 4) * 8;
  const int colb = lane & 15;
  const int rbase = wid * 16 + ((lane >> 4) << 2);

  for (int hg = 0; hg < 6; hg++){   // 2 heads per group
    f32x4 acc[12];
    #pragma unroll
    for (int n = 0; n < 12; n++) acc[n] = (f32x4)(0.f);

    for (int kc = 0; kc < 12; kc++){
      __syncthreads();
      #pragma unroll
      for (int u = tid; u < 768; u += 256){
        int row = u >> 2, cg = u & 3;
        int grow = (row >> 6) * DIM + hg * 64 + (row & 63);
        *(int4v*)&wbuf[row][cg * 8] =
            *(const int4v*)(qkvw + (size_t)grow * DIM + kc * 32 + cg * 8);
      }
      __syncthreads();
      #pragma unroll
      for (int n = 0; n < 12; n++){
        short8 bfr = *(const short8*)&wbuf[n * 16 + colb][kb];
        acc[n] = mfma16(afr[kc], bfr, acc[n]);
      }
    }

    // scatter to q/k (raw) and vT (+bias)
    #pragma unroll
    for (int n = 0; n < 12; n++){
      int c = n * 16 + colb;     // 0..191
      int seg = c >> 6;          // 0=q 1=k 2=v
      int cl = c & 63;
      int hh = cl >> 5, d = cl & 31;
      float bias = qkvb[seg * DIM + hg * 64 + cl];
      if (seg < 2){
        #pragma unroll
        for (int r = 0; r < 4; r++)
          qk[seg * 2 + hh][rbase + r][d] = __float2bfloat16(acc[n][r] + bias);
      } else {
        #pragma unroll
        for (int r = 0; r < 4; r++)
          vT[hh][d][rbase + r] = __float2bfloat16(acc[n][r] + bias);
      }
    }
    __syncthreads();

    // cosine-normalize q,k rows: 256 threads = 4 arrays x 64 rows
    {
      int a = tid >> 6, r = tid & 63;
      float s = 0.f;
      #pragma unroll
      for (int d = 0; d < 32; d++){
        float v = __bfloat162float(qk[a][r][d]); s += v * v;
      }
      float inv = 1.0f / fmaxf(sqrtf(s), 1e-12f);
      #pragma unroll
      for (int d = 0; d < 32; d++)
        qk[a][r][d] = __float2bfloat16(__bfloat162float(qk[a][r][d]) * inv);
    }
    __syncthreads();

    // attention: wave -> (head hh, row-half mh)
    {
      const int hh = wid & 1, mh = wid >> 1;
      const int head = hg * 2 + hh;
      const float sc = scalev[head];
      f32x4 sacc[2][4];
      #pragma unroll
      for (int mi = 0; mi < 2; mi++)
        #pragma unroll
        for (int ni = 0; ni < 4; ni++) sacc[mi][ni] = (f32x4)(0.f);
      short8 qf[2];
      #pragma unroll
      for (int mi = 0; mi < 2; mi++)
        qf[mi] = *(const short8*)&qk[hh][mh * 32 + mi * 16 + colb][kb];
      #pragma unroll
      for (int ni = 0; ni < 4; ni++){
        short8 kf = *(const short8*)&qk[2 + hh][ni * 16 + colb][kb];
        #pragma unroll
        for (int mi = 0; mi < 2; mi++)
          sacc[mi][ni] = mfma16(qf[mi], kf, sacc[mi][ni]);
      }
      const float* bptr = bias16 + (size_t)head * 4096;
      #pragma unroll
      for (int mi = 0; mi < 2; mi++){
        int rb = mh * 32 + mi * 16 + ((lane >> 4) << 2);
        #pragma unroll
        for (int r = 0; r < 4; r++){
          int rm = rb + r;
          int li = lblS[rm];
          float v[4]; float mx = -1e30f;
          #pragma unroll
          for (int ni = 0; ni < 4; ni++){
            int cn = ni * 16 + colb;
            float t = sacc[mi][ni][r] * sc + bptr[rm * 64 + cn]
                      + ((lblS[cn] == li) ? 0.f : -100.f);
            v[ni] = t; mx = fmaxf(mx, t);
          }
          mx = wmax16(mx);
          float s = 0.f;
          #pragma unroll
          for (int ni = 0; ni < 4; ni++){ v[ni] = __expf(v[ni] - mx); s += v[ni]; }
          s = wsum16(s);
          float is = 1.0f / s;
          #pragma unroll
          for (int ni = 0; ni < 4; ni++)
            Pb[hh][rm][ni * 16 + colb] = __float2bfloat16(v[ni] * is);
        }
      }
      __syncthreads();
      f32x4 oacc[2][2];
      #pragma unroll
      for (int mi = 0; mi < 2; mi++)
        #pragma unroll
        for (int ni = 0; ni < 2; ni++) oacc[mi][ni] = (f32x4)(0.f);
      #pragma unroll
      for (int kc2 = 0; kc2 < 2; kc2++){
        short8 pf[2];
        #pragma unroll
        for (int mi = 0; mi < 2; mi++)
          pf[mi] = *(const short8*)&Pb[hh][mh * 32 + mi * 16 + colb][kc2 * 32 + kb];
        #pragma unroll
        for (int ni = 0; ni < 2; ni++){
          short8 vf = *(const short8*)&vT[hh][ni * 16 + colb][kc2 * 32 + kb];
          #pragma unroll
          for (int mi = 0; mi < 2; mi++)
            oacc[mi][ni] = mfma16(pf[mi], vf, oacc[mi][ni]);
        }
      }
      #pragma unroll
      for (int mi = 0; mi < 2; mi++)
        #pragma unroll
        for (int ni = 0; ni < 2; ni++)
          #pragma unroll
          for (int r = 0; r < 4; r++){
            int rm = mh * 32 + mi * 16 + ((lane >> 4) << 2) + r;
            int c = head * HD + ni * 16 + colb;
            attnout[((size_t)wi * 64 + rm) * DIM + c] = __float2bfloat16(oacc[mi][ni][r]);
          }
    }
    __syncthreads();
  }
}

// ---------------- proj + unwindow/unshift + residual + LN1 ----------------
__global__ __launch_bounds__(256, 1) void k_proj(
    const __hip_bfloat16* __restrict__ attnout,
    const __hip_bfloat16* __restrict__ projw,
    const float* __restrict__ projb,
    const float* __restrict__ x,
    const float* __restrict__ g1, const float* __restrict__ b1v,
    __hip_bfloat16* __restrict__ y)
{
  __shared__ __hip_bfloat16 wbuf[384][40];
  const int tid = threadIdx.x, lane = tid & 63, wid = tid >> 6;
  const int wi = blockIdx.x;
  const int kb = (lane >> 4) * 8, colb = lane & 15;
  const int rbase = wid * 16 + ((lane >> 4) << 2);

  short8 afr[12];
  {
    const __hip_bfloat16* ap = attnout + ((size_t)wi * 64 + wid * 16 + colb) * DIM;
    #pragma unroll
    for (int kc = 0; kc < 12; kc++)
      afr[kc] = *(const short8*)(ap + kc * 32 + kb);
  }

  f32x4 acc[24];
  #pragma unroll
  for (int n = 0; n < 24; n++) acc[n] = (f32x4)(0.f);

  for (int kc = 0; kc < 12; kc++){
    __syncthreads();
    #pragma unroll
    for (int u = tid; u < 1536; u += 256){
      int row = u >> 2, cg = u & 3;
      *(int4v*)&wbuf[row][cg * 8] =
          *(const int4v*)(projw + (size_t)row * DIM + kc * 32 + cg * 8);
    }
    __syncthreads();
    #pragma unroll
    for (int n = 0; n < 24; n++){
      short8 bfr = *(const short8*)&wbuf[n * 16 + colb][kb];
      acc[n] = mfma16(afr[kc], bfr, acc[n]);
    }
  }

  float s1[4] = {0,0,0,0}, s2[4] = {0,0,0,0};
  #pragma unroll
  for (int n = 0; n < 24; n++){
    float pb = projb[n * 16 + colb];
    #pragma unroll
    for (int r = 0; r < 4; r++){
      float v = acc[n][r] + pb; acc[n][r] = v;
      s1[r] += v; s2[r] += v * v;
    }
  }
  #pragma unroll
  for (int r = 0; r < 4; r++){ s1[r] = wsum16(s1[r]); s2[r] = wsum16(s2[r]); }

  const int bb = wi >> 6, wh = (wi >> 3) & 7, ww = wi & 7;
  #pragma unroll
  for (int r = 0; r < 4; r++){
    int t = rbase + r;
    int rr = t >> 3, cc = t & 7;
    int h = (wh * 8 + rr + 4) & 63, w = (ww * 8 + cc + 4) & 63;
    size_t gpos = (size_t)(bb << 12) + (h << 6) + w;
    float mean = s1[r] * (1.f / 384.f);
    float var = s2[r] * (1.f / 384.f) - mean * mean;
    float inv = rsqrtf(var + 1e-5f);
    const float* xp = x + gpos * DIM;
    __hip_bfloat16* yp = y + gpos * DIM;
    #pragma unroll
    for (int n = 0; n < 24; n++){
      int c = n * 16 + colb;
      float ln = (acc[n][r] - mean) * inv * g1[c] + b1v[c];
      yp[c] = __float2bfloat16(xp[c] + ln);
    }
  }
}

// -------- fused MLP (fc1+gelu+fc2) + LN2 + residual, 2-phase pipelined -----
// M=128 rows/block, 512 threads (8 waves x 16 rows). Hidden chunk CH=96.
// Weights staged in MFMA-fragment order via global_load_lds (linear LDS,
// per-lane global source) -> bank-conflict-free reads at base + lane*16.
#define MLP_CH 96
#define NCH 16           // 1536 / 96
__global__ __launch_bounds__(512, 2) void k_mlp(
    const __hip_bfloat16* __restrict__ y,
    const __hip_bfloat16* __restrict__ fc1w, const float* __restrict__ fc1b,
    const __hip_bfloat16* __restrict__ fc2w, const float* __restrict__ fc2b,
    const float* __restrict__ g2, const float* __restrict__ b2v,
    float* __restrict__ out)
{
  __shared__ char wstage[2][12 * 1024];        // 24 KB: 12 frag-slots x 64 lanes x 16B
  __shared__ __hip_bfloat16 hbuf[128][104];    // 26.6 KB, 13x16B row stride (odd quads)

  const int tid = threadIdx.x, lane = tid & 63, wid = tid >> 6;
  const int colb = lane & 15;
  const int hi = lane >> 4;          // 0..3
  const int kb = hi * 8;
  const size_t row0 = (size_t)blockIdx.x * 128;

  // A fragments of y for this wave's 16 rows: afr[kidx], kidx = k/32
  short8 afr[12];
  {
    const __hip_bfloat16* ap = y + (row0 + wid * 16 + colb) * DIM;
    #pragma unroll
    for (int kc = 0; kc < 12; kc++)
      afr[kc] = *(const short8*)(ap + kc * 32 + kb);
  }

  // stage helpers: 12 slots per round, wave handles slots wid, wid+8
  auto stage_fc1 = [&](int buf, int ch, int kc){
    for (int s = wid; s < 12; s += 8){
      int kk = s / 6, n = s % 6;
      int row = ch * MLP_CH + n * 16 + colb;
      int col = kc * 64 + kk * 32 + kb;
      gload16(fc1w + (size_t)row * DIM + col, &wstage[buf][s * 1024]);
    }
  };
  auto stage_fc2 = [&](int buf, int ch, int r2){
    int ks = r2 >> 1, half = r2 & 1;
    for (int s = wid; s < 12; s += 8){
      int row = half * 192 + s * 16 + colb;
      int col = ch * MLP_CH + ks * 32 + kb;
      gload16(fc2w + (size_t)row * 1536 + col, &wstage[buf][s * 1024]);
    }
  };

  f32x4 acc2[24];
  #pragma unroll
  for (int n = 0; n < 24; n++) acc2[n] = (f32x4)(0.f);

  int cur = 0;
  stage_fc1(0, 0, 0);
  __syncthreads();

  for (int ch = 0; ch < NCH; ch++){
    f32x4 acc1[6];
    #pragma unroll
    for (int n = 0; n < 6; n++) acc1[n] = (f32x4)(0.f);

    #pragma unroll
    for (int r = 0; r < 6; r++){
      if (r < 5) stage_fc1(cur ^ 1, ch, r + 1);
      else       stage_fc2(cur ^ 1, ch, 0);
      #pragma unroll
      for (int kk = 0; kk < 2; kk++)
        #pragma unroll
        for (int n = 0; n < 6; n++){
          short8 b = *(const short8*)&wstage[cur][(kk * 6 + n) * 1024 + lane * 16];
          acc1[n] = mfma16(afr[r * 2 + kk], b, acc1[n]);
        }
      __syncthreads();
      cur ^= 1;
    }

    // GELU -> hbuf
    #pragma unroll
    for (int n = 0; n < 6; n++){
      float fb = fc1b[ch * MLP_CH + n * 16 + colb];
      #pragma unroll
      for (int r = 0; r < 4; r++){
        float v = acc1[n][r] + fb;
        float gl = 0.5f * v * (1.0f + erff(v * 0.70710678118654752f));
        hbuf[wid * 16 + hi * 4 + r][n * 16 + colb] = __float2bfloat16(gl);
      }
    }
    __syncthreads();

    short8 hfr;
    #pragma unroll
    for (int r = 0; r < 6; r++){
      int ks = r >> 1, half = r & 1;
      if (r < 5)           stage_fc2(cur ^ 1, ch, r + 1);
      else if (ch < NCH-1) stage_fc1(cur ^ 1, ch + 1, 0);
      if (half == 0)
        hfr = *(const short8*)&hbuf[wid * 16 + colb][ks * 32 + kb];
      #pragma unroll
      for (int n = 0; n < 12; n++){
        short8 b = *(const short8*)&wstage[cur][n * 1024 + lane * 16];
        acc2[half * 12 + n] = mfma16(hfr, b, acc2[half * 12 + n]);
      }
      __syncthreads();
      cur ^= 1;
    }
  }

  // LN2 + residual epilogue
  float s1[4] = {0,0,0,0}, s2[4] = {0,0,0,0};
  #pragma unroll
  for (int n = 0; n < 24; n++){
    float fb = fc2b[n * 16 + colb];
    #pragma unroll
    for (int r = 0; r < 4; r++){
      float v = acc2[n][r] + fb; acc2[n][r] = v;
      s1[r] += v; s2[r] += v * v;
    }
  }
  #pragma unroll
  for (int r = 0; r < 4; r++){ s1[r] = wsum16(s1[r]); s2[r] = wsum16(s2[r]); }
  #pragma unroll
  for (int r = 0; r < 4; r++){
    size_t grow = row0 + wid * 16 + hi * 4 + r;
    float mean = s1[r] * (1.f / 384.f);
    float var = s2[r] * (1.f / 384.f) - mean * mean;
    float inv = rsqrtf(var + 1e-5f);
    const __hip_bfloat16* yp = y + grow * DIM;
    float* op = out + grow * DIM;
    #pragma unroll
    for (int n = 0; n < 24; n++){
      int c = n * 16 + colb;
      float ln = (acc2[n][r] - mean) * inv * g2[c] + b2v[c];
      op[c] = __bfloat162float(yp[c]) + ln;
    }
  }
}

extern "C" void kernel_launch(void* const* d_in, const int* in_sizes, int n_in,
                              void* d_out, int out_size, void* d_ws, size_t ws_size,
                              hipStream_t stream)
{
  (void)in_sizes; (void)n_in; (void)out_size; (void)ws_size;
  const float* x    = (const float*)d_in[0];
  const float* qkvw_f = (const float*)d_in[3];
  const float* qkvb = (const float*)d_in[4];
  const float* lsc  = (const float*)d_in[5];
  const float* cw1  = (const float*)d_in[6];
  const float* cb1  = (const float*)d_in[7];
  const float* cw2  = (const float*)d_in[8];
  const float* pw   = (const float*)d_in[9];
  const float* pb   = (const float*)d_in[10];
  const float* g1   = (const float*)d_in[11];
  const float* b1   = (const float*)d_in[12];
  const float* g2   = (const float*)d_in[13];
  const float* b2   = (const float*)d_in[14];
  const float* f1w  = (const float*)d_in[15];
  const float* f1b  = (const float*)d_in[16];
  const float* f2w  = (const float*)d_in[17];
  const float* f2b  = (const float*)d_in[18];

  char* ws = (char*)d_ws;
  size_t off = 0;
  auto alloc = [&](size_t bytes) -> char* {
    char* p = ws + off;
    off += (bytes + 255) & ~(size_t)255;
    return p;
  };
  __hip_bfloat16* qkvw_h  = (__hip_bfloat16*)alloc((size_t)1152 * 384 * 2);
  __hip_bfloat16* projw_h = (__hip_bfloat16*)alloc((size_t)384 * 384 * 2);
  __hip_bfloat16* fc1w_h  = (__hip_bfloat16*)alloc((size_t)1536 * 384 * 2);
  __hip_bfloat16* fc2w_h  = (__hip_bfloat16*)alloc((size_t)384 * 1536 * 2);
  float* scalev = (float*)alloc(NH * 4);
  float* hbias  = (float*)alloc(225 * NH * 4);
  float* bias16 = (float*)alloc((size_t)NH * 64 * 64 * 4);
  __hip_bfloat16* attnout = (__hip_bfloat16*)alloc((size_t)2048 * 64 * 384 * 2);
  __hip_bfloat16* yb      = (__hip_bfloat16*)alloc((size_t)131072 * 384 * 2);

  k_f32_to_bf16<<<512, 256, 0, stream>>>(qkvw_f, qkvw_h, 1152 * 384);
  k_f32_to_bf16<<<256, 256, 0, stream>>>(pw, projw_h, 384 * 384);
  k_f32_to_bf16<<<512, 256, 0, stream>>>(f1w, fc1w_h, 1536 * 384);
  k_f32_to_bf16<<<512, 256, 0, stream>>>(f2w, fc2w_h, 384 * 1536);
  k_cpb<<<225, 256, 0, stream>>>(cw1, cb1, cw2, hbias);
  k_bias16<<<192, 256, 0, stream>>>(hbias, lsc, bias16, scalev);
  k_attn<<<2048, 256, 0, stream>>>(x, qkvw_h, qkvb, scalev, bias16, attnout);
  k_proj<<<2048, 256, 0, stream>>>(attnout, projw_h, pb, x, g1, b1, yb);
  k_mlp<<<1024, 512, 0, stream>>>(yb, fc1w_h, f1b, fc2w_h, f2b, g2, b2, (float*)d_out);
}

// Round 3
// 1527.709 us; speedup vs baseline: 1.5851x; 1.0628x over previous
//
#include <hip/hip_runtime.h>
#include <hip/hip_bf16.h>
#include <math.h>

typedef __attribute__((ext_vector_type(8))) short short8;
typedef __attribute__((ext_vector_type(4))) float f32x4;
typedef __attribute__((ext_vector_type(4))) int int4v;

#define NH 12
#define DIM 384
#define HD 32

__device__ inline f32x4 mfma16(short8 a, short8 b, f32x4 c){
  return __builtin_amdgcn_mfma_f32_16x16x32_bf16(a, b, c, 0, 0, 0);
}

__device__ inline short fbits(float f){
  __hip_bfloat16 h = __float2bfloat16(f);
  short s; __builtin_memcpy(&s, &h, 2); return s;
}

__device__ inline float wsum16(float v){
  #pragma unroll
  for (int off = 1; off < 16; off <<= 1) v += __shfl_xor(v, off);
  return v;
}
__device__ inline float wmax16(float v){
  #pragma unroll
  for (int off = 1; off < 16; off <<= 1) v = fmaxf(v, __shfl_xor(v, off));
  return v;
}

__device__ inline void gload16(const void* g, void* l){
  __builtin_amdgcn_global_load_lds(
      (const __attribute__((address_space(1))) unsigned int*)g,
      (__attribute__((address_space(3))) unsigned int*)l, 16, 0, 0);
}

__global__ void k_f32_to_bf16(const float* __restrict__ src,
                              __hip_bfloat16* __restrict__ dst, int n){
  int i = blockIdx.x * blockDim.x + threadIdx.x;
  int stride = gridDim.x * blockDim.x;
  for (; i < n; i += stride) dst[i] = __float2bfloat16(src[i]);
}

__device__ inline float cpbf(int a){
  float v = (float)a * (8.0f / 7.0f);
  float s = (v > 0.f) ? 1.f : ((v < 0.f) ? -1.f : 0.f);
  return s * log2f(fabsf(v) + 1.0f) * (1.0f / 3.0f);
}

__global__ __launch_bounds__(256) void k_cpb(
    const float* __restrict__ w1, const float* __restrict__ b1,
    const float* __restrict__ w2, float* __restrict__ hbias)
{
  __shared__ float hid[512];
  int t = blockIdx.x;  // 0..224
  float t0 = cpbf(t / 15 - 7), t1 = cpbf(t % 15 - 7);
  for (int j = threadIdx.x; j < 512; j += 256)
    hid[j] = fmaxf(w1[j * 2 + 0] * t0 + w1[j * 2 + 1] * t1 + b1[j], 0.f);
  __syncthreads();
  if (threadIdx.x < NH){
    float s = 0.f;
    for (int j = 0; j < 512; j++) s += hid[j] * w2[threadIdx.x * 512 + j];
    hbias[t * NH + threadIdx.x] = s;
  }
}

__global__ void k_bias16(const float* __restrict__ hbias,
                         const float* __restrict__ logit_scale,
                         float* __restrict__ bias16, float* __restrict__ scalev)
{
  int i = blockIdx.x * blockDim.x + threadIdx.x;
  if (i < NH) scalev[i] = expf(fminf(logit_scale[i], logf(100.0f)));
  if (i >= NH * 64 * 64) return;
  int h = i >> 12, r = (i >> 6) & 63, c = i & 63;
  int t = ((r >> 3) - (c >> 3) + 7) * 15 + ((r & 7) - (c & 7) + 7);
  float b = hbias[t * NH + h];
  bias16[i] = 16.0f / (1.0f + expf(-b));
}

// ---------------- attention: one workgroup per 8x8 window ----------------
__global__ __launch_bounds__(256, 1) void k_attn(
    const float* __restrict__ x,
    const __hip_bfloat16* __restrict__ qkvw,
    const float* __restrict__ qkvb,
    const float* __restrict__ scalev,
    const float* __restrict__ bias16,
    __hip_bfloat16* __restrict__ attnout)
{
  __shared__ __hip_bfloat16 wbuf[192][40];   // weight k-chunk
  __shared__ __hip_bfloat16 qk[4][64][40];   // q0,q1,k0,k1
  __shared__ __hip_bfloat16 vT[2][32][72];   // v transposed [d][token]
  __shared__ __hip_bfloat16 Pb[2][64][72];   // softmax P
  __shared__ int lblS[64];

  const int tid = threadIdx.x;
  const int lane = tid & 63;
  const int wid = tid >> 6;
  const int wi = blockIdx.x;
  const int bb = wi >> 6, wh = (wi >> 3) & 7, ww = wi & 7;

  if (tid < 64){
    int rr = tid >> 3, cc = tid & 7;
    int hs = wh * 8 + rr, ws2 = ww * 8 + cc;
    int rh = (hs < 56) ? 0 : (hs < 60 ? 1 : 2);
    int rw = (ws2 < 56) ? 0 : (ws2 < 60 ? 1 : 2);
    lblS[tid] = rh * 3 + rw;
  }

  // A fragments (window tokens) in registers; reused for q,k,v GEMMs
  short8 afr[12];
  {
    int t = wid * 16 + (lane & 15);
    int rr = t >> 3, cc = t & 7;
    int h = (wh * 8 + rr + 4) & 63, w = (ww * 8 + cc + 4) & 63;
    const float4* p = (const float4*)(x + ((size_t)((bb << 12) + (h << 6) + w)) * DIM);
    int kb4 = (lane >> 4) * 2;
    #pragma unroll
    for (int kc = 0; kc < 12; kc++){
      float4 f0 = p[kc * 8 + kb4];
      float4 f1 = p[kc * 8 + kb4 + 1];
      short8 s;
      s[0] = fbits(f0.x); s[1] = fbits(f0.y); s[2] = fbits(f0.z); s[3] = fbits(f0.w);
      s[4] = fbits(f1.x); s[5] = fbits(f1.y); s[6] = fbits(f1.z); s[7] = fbits(f1.w);
      afr[kc] = s;
    }
  }

  const int kb = (lane >> 4) * 8;
  const int colb = lane & 15;
  const int rbase = wid * 16 + ((lane >> 4) << 2);

  for (int hg = 0; hg < 6; hg++){   // 2 heads per group
    f32x4 acc[12];
    #pragma unroll
    for (int n = 0; n < 12; n++) acc[n] = (f32x4)(0.f);

    for (int kc = 0; kc < 12; kc++){
      __syncthreads();
      #pragma unroll
      for (int u = tid; u < 768; u += 256){
        int row = u >> 2, cg = u & 3;
        int grow = (row >> 6) * DIM + hg * 64 + (row & 63);
        *(int4v*)&wbuf[row][cg * 8] =
            *(const int4v*)(qkvw + (size_t)grow * DIM + kc * 32 + cg * 8);
      }
      __syncthreads();
      #pragma unroll
      for (int n = 0; n < 12; n++){
        short8 bfr = *(const short8*)&wbuf[n * 16 + colb][kb];
        acc[n] = mfma16(afr[kc], bfr, acc[n]);
      }
    }

    // scatter to q/k (raw) and vT (+bias)
    #pragma unroll
    for (int n = 0; n < 12; n++){
      int c = n * 16 + colb;     // 0..191
      int seg = c >> 6;          // 0=q 1=k 2=v
      int cl = c & 63;
      int hh = cl >> 5, d = cl & 31;
      float bias = qkvb[seg * DIM + hg * 64 + cl];
      if (seg < 2){
        #pragma unroll
        for (int r = 0; r < 4; r++)
          qk[seg * 2 + hh][rbase + r][d] = __float2bfloat16(acc[n][r] + bias);
      } else {
        #pragma unroll
        for (int r = 0; r < 4; r++)
          vT[hh][d][rbase + r] = __float2bfloat16(acc[n][r] + bias);
      }
    }
    __syncthreads();

    // cosine-normalize q,k rows: 256 threads = 4 arrays x 64 rows
    {
      int a = tid >> 6, r = tid & 63;
      float s = 0.f;
      #pragma unroll
      for (int d = 0; d < 32; d++){
        float v = __bfloat162float(qk[a][r][d]); s += v * v;
      }
      float inv = 1.0f / fmaxf(sqrtf(s), 1e-12f);
      #pragma unroll
      for (int d = 0; d < 32; d++)
        qk[a][r][d] = __float2bfloat16(__bfloat162float(qk[a][r][d]) * inv);
    }
    __syncthreads();

    // attention: wave -> (head hh, row-half mh)
    {
      const int hh = wid & 1, mh = wid >> 1;
      const int head = hg * 2 + hh;
      const float sc = scalev[head];
      f32x4 sacc[2][4];
      #pragma unroll
      for (int mi = 0; mi < 2; mi++)
        #pragma unroll
        for (int ni = 0; ni < 4; ni++) sacc[mi][ni] = (f32x4)(0.f);
      short8 qf[2];
      #pragma unroll
      for (int mi = 0; mi < 2; mi++)
        qf[mi] = *(const short8*)&qk[hh][mh * 32 + mi * 16 + colb][kb];
      #pragma unroll
      for (int ni = 0; ni < 4; ni++){
        short8 kf = *(const short8*)&qk[2 + hh][ni * 16 + colb][kb];
        #pragma unroll
        for (int mi = 0; mi < 2; mi++)
          sacc[mi][ni] = mfma16(qf[mi], kf, sacc[mi][ni]);
      }
      const float* bptr = bias16 + (size_t)head * 4096;
      #pragma unroll
      for (int mi = 0; mi < 2; mi++){
        int rb = mh * 32 + mi * 16 + ((lane >> 4) << 2);
        #pragma unroll
        for (int r = 0; r < 4; r++){
          int rm = rb + r;
          int li = lblS[rm];
          float v[4]; float mx = -1e30f;
          #pragma unroll
          for (int ni = 0; ni < 4; ni++){
            int cn = ni * 16 + colb;
            float t = sacc[mi][ni][r] * sc + bptr[rm * 64 + cn]
                      + ((lblS[cn] == li) ? 0.f : -100.f);
            v[ni] = t; mx = fmaxf(mx, t);
          }
          mx = wmax16(mx);
          float s = 0.f;
          #pragma unroll
          for (int ni = 0; ni < 4; ni++){ v[ni] = __expf(v[ni] - mx); s += v[ni]; }
          s = wsum16(s);
          float is = 1.0f / s;
          #pragma unroll
          for (int ni = 0; ni < 4; ni++)
            Pb[hh][rm][ni * 16 + colb] = __float2bfloat16(v[ni] * is);
        }
      }
      __syncthreads();
      f32x4 oacc[2][2];
      #pragma unroll
      for (int mi = 0; mi < 2; mi++)
        #pragma unroll
        for (int ni = 0; ni < 2; ni++) oacc[mi][ni] = (f32x4)(0.f);
      #pragma unroll
      for (int kc2 = 0; kc2 < 2; kc2++){
        short8 pf[2];
        #pragma unroll
        for (int mi = 0; mi < 2; mi++)
          pf[mi] = *(const short8*)&Pb[hh][mh * 32 + mi * 16 + colb][kc2 * 32 + kb];
        #pragma unroll
        for (int ni = 0; ni < 2; ni++){
          short8 vf = *(const short8*)&vT[hh][ni * 16 + colb][kc2 * 32 + kb];
          #pragma unroll
          for (int mi = 0; mi < 2; mi++)
            oacc[mi][ni] = mfma16(pf[mi], vf, oacc[mi][ni]);
        }
      }
      #pragma unroll
      for (int mi = 0; mi < 2; mi++)
        #pragma unroll
        for (int ni = 0; ni < 2; ni++)
          #pragma unroll
          for (int r = 0; r < 4; r++){
            int rm = mh * 32 + mi * 16 + ((lane >> 4) << 2) + r;
            int c = head * HD + ni * 16 + colb;
            attnout[((size_t)wi * 64 + rm) * DIM + c] = __float2bfloat16(oacc[mi][ni][r]);
          }
    }
    __syncthreads();
  }
}

// ------ proj + unwindow/unshift + residual + LN1 (4Mx2N waves, dbuf) ------
__global__ __launch_bounds__(512, 2) void k_proj(
    const __hip_bfloat16* __restrict__ attnout,
    const __hip_bfloat16* __restrict__ projw,
    const float* __restrict__ projb,
    const float* __restrict__ x,
    const float* __restrict__ g1, const float* __restrict__ b1v,
    __hip_bfloat16* __restrict__ yout)
{
  __shared__ __attribute__((aligned(16))) char stage[2][12288];
  __shared__ float lnred[128][4];

  const int tid = threadIdx.x, lane = tid & 63, wid = tid >> 6;
  const int colb = lane & 15, hi = lane >> 4;
  const int wm = wid >> 1, wn = wid & 1;
  const size_t row0 = (size_t)blockIdx.x * 128;

  // A fragments: 32 rows/wave, all K in registers
  short8 afr[2][12];
  #pragma unroll
  for (int mi = 0; mi < 2; mi++){
    const __hip_bfloat16* ap = attnout + (row0 + wm * 32 + mi * 16 + colb) * DIM + hi * 8;
    #pragma unroll
    for (int kc = 0; kc < 12; kc++)
      afr[mi][kc] = *(const short8*)(ap + kc * 32);
  }

  f32x4 acc[24];
  #pragma unroll
  for (int i = 0; i < 24; i++) acc[i] = (f32x4)(0.f);

  auto stage_p = [&](int buf, int q){
    int kc = q >> 1, half = q & 1;
    for (int s = wid; s < 12; s += 8)
      gload16(projw + (size_t)(half * 192 + s * 16 + colb) * DIM + kc * 32 + hi * 8,
              &stage[buf][s * 1024]);
  };

  int buf = 0;
  stage_p(0, 0);
  __syncthreads();

  #pragma unroll
  for (int q = 0; q < 24; q++){
    if (q < 23) stage_p(buf ^ 1, q + 1);
    if (wn == (q & 1)){
      const int kc = q >> 1;
      #pragma unroll
      for (int n = 0; n < 12; n++){
        short8 b = *(const short8*)&stage[buf][n * 1024 + lane * 16];
        #pragma unroll
        for (int mi = 0; mi < 2; mi++)
          acc[mi * 12 + n] = mfma16(afr[mi][kc], b, acc[mi * 12 + n]);
      }
    }
    __syncthreads(); buf ^= 1;
  }

  // bias + LN partial sums
  float s1v[2][4], s2v[2][4];
  #pragma unroll
  for (int mi = 0; mi < 2; mi++)
    #pragma unroll
    for (int rr = 0; rr < 4; rr++){ s1v[mi][rr] = 0.f; s2v[mi][rr] = 0.f; }
  #pragma unroll
  for (int n = 0; n < 12; n++){
    float pb = projb[wn * 192 + n * 16 + colb];
    #pragma unroll
    for (int mi = 0; mi < 2; mi++)
      #pragma unroll
      for (int rr = 0; rr < 4; rr++){
        float v = acc[mi * 12 + n][rr] + pb;
        acc[mi * 12 + n][rr] = v;
        s1v[mi][rr] += v; s2v[mi][rr] += v * v;
      }
  }
  #pragma unroll
  for (int mi = 0; mi < 2; mi++)
    #pragma unroll
    for (int rr = 0; rr < 4; rr++){
      float a = wsum16(s1v[mi][rr]);
      float b = wsum16(s2v[mi][rr]);
      if (colb == 0){
        int row = wm * 32 + mi * 16 + hi * 4 + rr;
        lnred[row][wn * 2 + 0] = a;
        lnred[row][wn * 2 + 1] = b;
      }
    }
  __syncthreads();

  #pragma unroll
  for (int mi = 0; mi < 2; mi++)
    #pragma unroll
    for (int rr = 0; rr < 4; rr++){
      int row = wm * 32 + mi * 16 + hi * 4 + rr;
      float t1 = lnred[row][0] + lnred[row][2];
      float t2 = lnred[row][1] + lnred[row][3];
      float mean = t1 * (1.f / 384.f);
      float var  = t2 * (1.f / 384.f) - mean * mean;
      float inv  = rsqrtf(var + 1e-5f);
      size_t arow = row0 + row;             // attnout (windowed) row
      int wi2 = (int)(arow >> 6), t = (int)(arow & 63);
      int bb = wi2 >> 6, wh = (wi2 >> 3) & 7, ww = wi2 & 7;
      int rr2 = t >> 3, cc = t & 7;
      int h = (wh * 8 + rr2 + 4) & 63, w = (ww * 8 + cc + 4) & 63;
      size_t gpos = ((size_t)bb << 12) + (h << 6) + w;
      const float* xp = x + gpos * DIM;
      __hip_bfloat16* yp = yout + gpos * DIM;
      #pragma unroll
      for (int n = 0; n < 12; n++){
        int c = wn * 192 + n * 16 + colb;
        float ln = (acc[mi * 12 + n][rr] - mean) * inv * g1[c] + b1v[c];
        yp[c] = __float2bfloat16(xp[c] + ln);
      }
    }
}

// -------- fused MLP (fc1+gelu+fc2) + LN2 + residual, 4Mx2N, dbuf ----------
__global__ __launch_bounds__(512, 2) void k_mlp(
    const __hip_bfloat16* __restrict__ y,
    const __hip_bfloat16* __restrict__ fc1w, const float* __restrict__ fc1b,
    const __hip_bfloat16* __restrict__ fc2w, const float* __restrict__ fc2b,
    const float* __restrict__ g2, const float* __restrict__ b2v,
    float* __restrict__ out)
{
  __shared__ __attribute__((aligned(16))) char stage[2][12288];  // 24 KB
  __shared__ __attribute__((aligned(16))) char htile[16384];     // 16 frag slots
  __shared__ float lnred[128][4];

  const int tid = threadIdx.x, lane = tid & 63, wid = tid >> 6;
  const int colb = lane & 15, hi = lane >> 4;
  const int wm = wid >> 1, wn = wid & 1;
  const size_t row0 = (size_t)blockIdx.x * 128;

  // A fragments of y: 32 rows/wave, full K in registers
  short8 afr[2][12];
  #pragma unroll
  for (int mi = 0; mi < 2; mi++){
    const __hip_bfloat16* ap = y + (row0 + wm * 32 + mi * 16 + colb) * DIM + hi * 8;
    #pragma unroll
    for (int kc = 0; kc < 12; kc++)
      afr[mi][kc] = *(const short8*)(ap + kc * 32);
  }

  auto stage_fc1 = [&](int buf, int ch, int r){
    // 12 slots: kk3 = s>>2 (kc = r*3+kk3), nf = s&3 (16-col group of 64-chunk)
    for (int s = wid; s < 12; s += 8){
      int kk3 = s >> 2, nf = s & 3;
      gload16(fc1w + (size_t)(ch * 64 + nf * 16 + colb) * DIM + (r * 3 + kk3) * 32 + hi * 8,
              &stage[buf][s * 1024]);
    }
  };
  auto stage_fc2 = [&](int buf, int ch, int fr){
    int kk = fr >> 1, half = fr & 1;
    for (int s = wid; s < 12; s += 8)
      gload16(fc2w + (size_t)(half * 192 + s * 16 + colb) * 1536 + ch * 64 + kk * 32 + hi * 8,
              &stage[buf][s * 1024]);
  };

  f32x4 acc2[24];
  #pragma unroll
  for (int i = 0; i < 24; i++) acc2[i] = (f32x4)(0.f);

  int buf = 0;
  stage_fc1(0, 0, 0);
  __syncthreads();

  for (int ch = 0; ch < 24; ch++){
    f32x4 acc1[2][2];
    acc1[0][0] = acc1[0][1] = acc1[1][0] = acc1[1][1] = (f32x4)(0.f);

    // ---- fc1: 4 rounds, K=96 each ----
    #pragma unroll
    for (int r = 0; r < 4; r++){
      if (r < 3) stage_fc1(buf ^ 1, ch, r + 1);
      else       stage_fc2(buf ^ 1, ch, 0);
      #pragma unroll
      for (int kk3 = 0; kk3 < 3; kk3++)
        #pragma unroll
        for (int nf2 = 0; nf2 < 2; nf2++){
          short8 b = *(const short8*)&stage[buf][(kk3 * 4 + wn * 2 + nf2) * 1024 + lane * 16];
          #pragma unroll
          for (int mi = 0; mi < 2; mi++)
            acc1[mi][nf2] = mfma16(afr[mi][r * 3 + kk3], b, acc1[mi][nf2]);
        }
      __syncthreads(); buf ^= 1;
    }

    // ---- fc2 rounds (GELU embedded in fr==0) ----
    #pragma unroll
    for (int fr = 0; fr < 4; fr++){
      if (fr == 0){
        // GELU -> htile (fragment-order for fc2 A-reads)
        #pragma unroll
        for (int mi = 0; mi < 2; mi++)
          #pragma unroll
          for (int nf2 = 0; nf2 < 2; nf2++){
            float fb = fc1b[ch * 64 + wn * 32 + nf2 * 16 + colb];
            #pragma unroll
            for (int rr = 0; rr < 4; rr++){
              float v = acc1[mi][nf2][rr] + fb;
              float u = v * (1.0f + 0.044715f * v * v);
              float gl = v / (1.0f + __expf(-1.5957691216f * u));
              int off = (wm * 2 + mi) * 2048 + wn * 1024
                      + (((hi * 4 + rr) | ((nf2 * 2 + (colb >> 3)) << 4)) << 4)
                      + ((colb & 7) << 1);
              *(__hip_bfloat16*)(htile + off) = __float2bfloat16(gl);
            }
          }
        __syncthreads();   // htile visible before reads
        stage_fc2(buf ^ 1, ch, 1);
      } else if (fr < 3){
        stage_fc2(buf ^ 1, ch, fr + 1);
      } else if (ch < 23){
        stage_fc1(buf ^ 1, ch + 1, 0);
      }
      if (wn == (fr & 1)){
        const int kk = fr >> 1;
        short8 hA[2];
        #pragma unroll
        for (int mi = 0; mi < 2; mi++)
          hA[mi] = *(const short8*)&htile[((wm * 2 + mi) * 2 + kk) * 1024 + lane * 16];
        #pragma unroll
        for (int n = 0; n < 12; n++){
          short8 b = *(const short8*)&stage[buf][n * 1024 + lane * 16];
          #pragma unroll
          for (int mi = 0; mi < 2; mi++)
            acc2[mi * 12 + n] = mfma16(hA[mi], b, acc2[mi * 12 + n]);
        }
      }
      __syncthreads(); buf ^= 1;
    }
  }

  // ---- LN2 + residual epilogue ----
  float s1v[2][4], s2v[2][4];
  #pragma unroll
  for (int mi = 0; mi < 2; mi++)
    #pragma unroll
    for (int rr = 0; rr < 4; rr++){ s1v[mi][rr] = 0.f; s2v[mi][rr] = 0.f; }
  #pragma unroll
  for (int n = 0; n < 12; n++){
    float fb = fc2b[wn * 192 + n * 16 + colb];
    #pragma unroll
    for (int mi = 0; mi < 2; mi++)
      #pragma unroll
      for (int rr = 0; rr < 4; rr++){
        float v = acc2[mi * 12 + n][rr] + fb;
        acc2[mi * 12 + n][rr] = v;
        s1v[mi][rr] += v; s2v[mi][rr] += v * v;
      }
  }
  #pragma unroll
  for (int mi = 0; mi < 2; mi++)
    #pragma unroll
    for (int rr = 0; rr < 4; rr++){
      float a = wsum16(s1v[mi][rr]);
      float b = wsum16(s2v[mi][rr]);
      if (colb == 0){
        int row = wm * 32 + mi * 16 + hi * 4 + rr;
        lnred[row][wn * 2 + 0] = a;
        lnred[row][wn * 2 + 1] = b;
      }
    }
  __syncthreads();

  #pragma unroll
  for (int mi = 0; mi < 2; mi++)
    #pragma unroll
    for (int rr = 0; rr < 4; rr++){
      int row = wm * 32 + mi * 16 + hi * 4 + rr;
      float t1 = lnred[row][0] + lnred[row][2];
      float t2 = lnred[row][1] + lnred[row][3];
      float mean = t1 * (1.f / 384.f);
      float var  = t2 * (1.f / 384.f) - mean * mean;
      float inv  = rsqrtf(var + 1e-5f);
      size_t grow = row0 + row;
      const __hip_bfloat16* yp = y + grow * DIM;
      float* op = out + grow * DIM;
      #pragma unroll
      for (int n = 0; n < 12; n++){
        int c = wn * 192 + n * 16 + colb;
        float ln = (acc2[mi * 12 + n][rr] - mean) * inv * g2[c] + b2v[c];
        op[c] = __bfloat162float(yp[c]) + ln;
      }
    }
}

extern "C" void kernel_launch(void* const* d_in, const int* in_sizes, int n_in,
                              void* d_out, int out_size, void* d_ws, size_t ws_size,
                              hipStream_t stream)
{
  (void)in_sizes; (void)n_in; (void)out_size; (void)ws_size;
  const float* x    = (const float*)d_in[0];
  const float* qkvw_f = (const float*)d_in[3];
  const float* qkvb = (const float*)d_in[4];
  const float* lsc  = (const float*)d_in[5];
  const float* cw1  = (const float*)d_in[6];
  const float* cb1  = (const float*)d_in[7];
  const float* cw2  = (const float*)d_in[8];
  const float* pw   = (const float*)d_in[9];
  const float* pb   = (const float*)d_in[10];
  const float* g1   = (const float*)d_in[11];
  const float* b1   = (const float*)d_in[12];
  const float* g2   = (const float*)d_in[13];
  const float* b2   = (const float*)d_in[14];
  const float* f1w  = (const float*)d_in[15];
  const float* f1b  = (const float*)d_in[16];
  const float* f2w  = (const float*)d_in[17];
  const float* f2b  = (const float*)d_in[18];

  char* ws = (char*)d_ws;
  size_t off = 0;
  auto alloc = [&](size_t bytes) -> char* {
    char* p = ws + off;
    off += (bytes + 255) & ~(size_t)255;
    return p;
  };
  __hip_bfloat16* qkvw_h  = (__hip_bfloat16*)alloc((size_t)1152 * 384 * 2);
  __hip_bfloat16* projw_h = (__hip_bfloat16*)alloc((size_t)384 * 384 * 2);
  __hip_bfloat16* fc1w_h  = (__hip_bfloat16*)alloc((size_t)1536 * 384 * 2);
  __hip_bfloat16* fc2w_h  = (__hip_bfloat16*)alloc((size_t)384 * 1536 * 2);
  float* scalev = (float*)alloc(NH * 4);
  float* hbias  = (float*)alloc(225 * NH * 4);
  float* bias16 = (float*)alloc((size_t)NH * 64 * 64 * 4);
  __hip_bfloat16* attnout = (__hip_bfloat16*)alloc((size_t)2048 * 64 * 384 * 2);
  __hip_bfloat16* yb      = (__hip_bfloat16*)alloc((size_t)131072 * 384 * 2);

  k_f32_to_bf16<<<512, 256, 0, stream>>>(qkvw_f, qkvw_h, 1152 * 384);
  k_f32_to_bf16<<<256, 256, 0, stream>>>(pw, projw_h, 384 * 384);
  k_f32_to_bf16<<<512, 256, 0, stream>>>(f1w, fc1w_h, 1536 * 384);
  k_f32_to_bf16<<<512, 256, 0, stream>>>(f2w, fc2w_h, 384 * 1536);
  k_cpb<<<225, 256, 0, stream>>>(cw1, cb1, cw2, hbias);
  k_bias16<<<192, 256, 0, stream>>>(hbias, lsc, bias16, scalev);
  k_attn<<<2048, 256, 0, stream>>>(x, qkvw_h, qkvb, scalev, bias16, attnout);
  k_proj<<<1024, 512, 0, stream>>>(attnout, projw_h, pb, x, g1, b1, yb);
  k_mlp<<<1024, 512, 0, stream>>>(yb, fc1w_h, f1b, fc2w_h, f2b, g2, b2, (float*)d_out);
}

// Round 4
// 1452.007 us; speedup vs baseline: 1.6677x; 1.0521x over previous
//
#include <hip/hip_runtime.h>
#include <hip/hip_bf16.h>
#include <math.h>

typedef __attribute__((ext_vector_type(8))) short short8;
typedef __attribute__((ext_vector_type(4))) float f32x4;
typedef __attribute__((ext_vector_type(4))) int int4v;

#define NH 12
#define DIM 384
#define HD 32

__device__ inline f32x4 mfma16(short8 a, short8 b, f32x4 c){
  return __builtin_amdgcn_mfma_f32_16x16x32_bf16(a, b, c, 0, 0, 0);
}

__device__ inline short fbits(float f){
  __hip_bfloat16 h = __float2bfloat16(f);
  short s; __builtin_memcpy(&s, &h, 2); return s;
}

__device__ inline float wsum16(float v){
  #pragma unroll
  for (int off = 1; off < 16; off <<= 1) v += __shfl_xor(v, off);
  return v;
}
__device__ inline float wmax16(float v){
  #pragma unroll
  for (int off = 1; off < 16; off <<= 1) v = fmaxf(v, __shfl_xor(v, off));
  return v;
}

__device__ inline void gload16(const void* g, void* l){
  __builtin_amdgcn_global_load_lds(
      (const __attribute__((address_space(1))) unsigned int*)g,
      (__attribute__((address_space(3))) unsigned int*)l, 16, 0, 0);
}

__global__ void k_f32_to_bf16(const float* __restrict__ src,
                              __hip_bfloat16* __restrict__ dst, int n){
  int i = blockIdx.x * blockDim.x + threadIdx.x;
  int stride = gridDim.x * blockDim.x;
  for (; i < n; i += stride) dst[i] = __float2bfloat16(src[i]);
}

__device__ inline float cpbf(int a){
  float v = (float)a * (8.0f / 7.0f);
  float s = (v > 0.f) ? 1.f : ((v < 0.f) ? -1.f : 0.f);
  return s * log2f(fabsf(v) + 1.0f) * (1.0f / 3.0f);
}

__global__ __launch_bounds__(256) void k_cpb(
    const float* __restrict__ w1, const float* __restrict__ b1,
    const float* __restrict__ w2, float* __restrict__ hbias)
{
  __shared__ float hid[512];
  int t = blockIdx.x;  // 0..224
  float t0 = cpbf(t / 15 - 7), t1 = cpbf(t % 15 - 7);
  for (int j = threadIdx.x; j < 512; j += 256)
    hid[j] = fmaxf(w1[j * 2 + 0] * t0 + w1[j * 2 + 1] * t1 + b1[j], 0.f);
  __syncthreads();
  if (threadIdx.x < NH){
    float s = 0.f;
    for (int j = 0; j < 512; j++) s += hid[j] * w2[threadIdx.x * 512 + j];
    hbias[t * NH + threadIdx.x] = s;
  }
}

__global__ void k_bias16(const float* __restrict__ hbias,
                         const float* __restrict__ logit_scale,
                         float* __restrict__ bias16, float* __restrict__ scalev)
{
  int i = blockIdx.x * blockDim.x + threadIdx.x;
  if (i < NH) scalev[i] = expf(fminf(logit_scale[i], logf(100.0f)));
  if (i >= NH * 64 * 64) return;
  int h = i >> 12, r = (i >> 6) & 63, c = i & 63;
  int t = ((r >> 3) - (c >> 3) + 7) * 15 + ((r & 7) - (c & 7) + 7);
  float b = hbias[t * NH + h];
  bias16[i] = 16.0f / (1.0f + expf(-b));
}

// ---------------- attention: one workgroup per 8x8 window ----------------
__global__ __launch_bounds__(256, 1) void k_attn(
    const float* __restrict__ x,
    const __hip_bfloat16* __restrict__ qkvw,
    const float* __restrict__ qkvb,
    const float* __restrict__ scalev,
    const float* __restrict__ bias16,
    __hip_bfloat16* __restrict__ attnout)
{
  __shared__ __hip_bfloat16 wbuf[192][40];   // weight k-chunk
  __shared__ __hip_bfloat16 qk[4][64][40];   // q0,q1,k0,k1
  __shared__ __hip_bfloat16 vT[2][32][72];   // v transposed [d][token]
  __shared__ __hip_bfloat16 Pb[2][64][72];   // softmax P
  __shared__ int lblS[64];

  const int tid = threadIdx.x;
  const int lane = tid & 63;
  const int wid = tid >> 6;
  const int wi = blockIdx.x;
  const int bb = wi >> 6, wh = (wi >> 3) & 7, ww = wi & 7;

  if (tid < 64){
    int rr = tid >> 3, cc = tid & 7;
    int hs = wh * 8 + rr, ws2 = ww * 8 + cc;
    int rh = (hs < 56) ? 0 : (hs < 60 ? 1 : 2);
    int rw = (ws2 < 56) ? 0 : (ws2 < 60 ? 1 : 2);
    lblS[tid] = rh * 3 + rw;
  }

  // A fragments (window tokens) in registers; reused for q,k,v GEMMs
  short8 afr[12];
  {
    int t = wid * 16 + (lane & 15);
    int rr = t >> 3, cc = t & 7;
    int h = (wh * 8 + rr + 4) & 63, w = (ww * 8 + cc + 4) & 63;
    const float4* p = (const float4*)(x + ((size_t)((bb << 12) + (h << 6) + w)) * DIM);
    int kb4 = (lane >> 4) * 2;
    #pragma unroll
    for (int kc = 0; kc < 12; kc++){
      float4 f0 = p[kc * 8 + kb4];
      float4 f1 = p[kc * 8 + kb4 + 1];
      short8 s;
      s[0] = fbits(f0.x); s[1] = fbits(f0.y); s[2] = fbits(f0.z); s[3] = fbits(f0.w);
      s[4] = fbits(f1.x); s[5] = fbits(f1.y); s[6] = fbits(f1.z); s[7] = fbits(f1.w);
      afr[kc] = s;
    }
  }

  const int kb = (lane >> 4) * 8;
  const int colb = lane & 15;
  const int rbase = wid * 16 + ((lane >> 4) << 2);

  for (int hg = 0; hg < 6; hg++){   // 2 heads per group
    f32x4 acc[12];
    #pragma unroll
    for (int n = 0; n < 12; n++) acc[n] = (f32x4)(0.f);

    for (int kc = 0; kc < 12; kc++){
      __syncthreads();
      #pragma unroll
      for (int u = tid; u < 768; u += 256){
        int row = u >> 2, cg = u & 3;
        int grow = (row >> 6) * DIM + hg * 64 + (row & 63);
        *(int4v*)&wbuf[row][cg * 8] =
            *(const int4v*)(qkvw + (size_t)grow * DIM + kc * 32 + cg * 8);
      }
      __syncthreads();
      #pragma unroll
      for (int n = 0; n < 12; n++){
        short8 bfr = *(const short8*)&wbuf[n * 16 + colb][kb];
        acc[n] = mfma16(afr[kc], bfr, acc[n]);
      }
    }

    // scatter to q/k (raw) and vT (+bias)
    #pragma unroll
    for (int n = 0; n < 12; n++){
      int c = n * 16 + colb;     // 0..191
      int seg = c >> 6;          // 0=q 1=k 2=v
      int cl = c & 63;
      int hh = cl >> 5, d = cl & 31;
      float bias = qkvb[seg * DIM + hg * 64 + cl];
      if (seg < 2){
        #pragma unroll
        for (int r = 0; r < 4; r++)
          qk[seg * 2 + hh][rbase + r][d] = __float2bfloat16(acc[n][r] + bias);
      } else {
        #pragma unroll
        for (int r = 0; r < 4; r++)
          vT[hh][d][rbase + r] = __float2bfloat16(acc[n][r] + bias);
      }
    }
    __syncthreads();

    // cosine-normalize q,k rows: 256 threads = 4 arrays x 64 rows
    {
      int a = tid >> 6, r = tid & 63;
      float s = 0.f;
      #pragma unroll
      for (int d = 0; d < 32; d++){
        float v = __bfloat162float(qk[a][r][d]); s += v * v;
      }
      float inv = 1.0f / fmaxf(sqrtf(s), 1e-12f);
      #pragma unroll
      for (int d = 0; d < 32; d++)
        qk[a][r][d] = __float2bfloat16(__bfloat162float(qk[a][r][d]) * inv);
    }
    __syncthreads();

    // attention: wave -> (head hh, row-half mh)
    {
      const int hh = wid & 1, mh = wid >> 1;
      const int head = hg * 2 + hh;
      const float sc = scalev[head];
      f32x4 sacc[2][4];
      #pragma unroll
      for (int mi = 0; mi < 2; mi++)
        #pragma unroll
        for (int ni = 0; ni < 4; ni++) sacc[mi][ni] = (f32x4)(0.f);
      short8 qf[2];
      #pragma unroll
      for (int mi = 0; mi < 2; mi++)
        qf[mi] = *(const short8*)&qk[hh][mh * 32 + mi * 16 + colb][kb];
      #pragma unroll
      for (int ni = 0; ni < 4; ni++){
        short8 kf = *(const short8*)&qk[2 + hh][ni * 16 + colb][kb];
        #pragma unroll
        for (int mi = 0; mi < 2; mi++)
          sacc[mi][ni] = mfma16(qf[mi], kf, sacc[mi][ni]);
      }
      const float* bptr = bias16 + (size_t)head * 4096;
      #pragma unroll
      for (int mi = 0; mi < 2; mi++){
        int rb = mh * 32 + mi * 16 + ((lane >> 4) << 2);
        #pragma unroll
        for (int r = 0; r < 4; r++){
          int rm = rb + r;
          int li = lblS[rm];
          float v[4]; float mx = -1e30f;
          #pragma unroll
          for (int ni = 0; ni < 4; ni++){
            int cn = ni * 16 + colb;
            float t = sacc[mi][ni][r] * sc + bptr[rm * 64 + cn]
                      + ((lblS[cn] == li) ? 0.f : -100.f);
            v[ni] = t; mx = fmaxf(mx, t);
          }
          mx = wmax16(mx);
          float s = 0.f;
          #pragma unroll
          for (int ni = 0; ni < 4; ni++){ v[ni] = __expf(v[ni] - mx); s += v[ni]; }
          s = wsum16(s);
          float is = 1.0f / s;
          #pragma unroll
          for (int ni = 0; ni < 4; ni++)
            Pb[hh][rm][ni * 16 + colb] = __float2bfloat16(v[ni] * is);
        }
      }
      __syncthreads();
      f32x4 oacc[2][2];
      #pragma unroll
      for (int mi = 0; mi < 2; mi++)
        #pragma unroll
        for (int ni = 0; ni < 2; ni++) oacc[mi][ni] = (f32x4)(0.f);
      #pragma unroll
      for (int kc2 = 0; kc2 < 2; kc2++){
        short8 pf[2];
        #pragma unroll
        for (int mi = 0; mi < 2; mi++)
          pf[mi] = *(const short8*)&Pb[hh][mh * 32 + mi * 16 + colb][kc2 * 32 + kb];
        #pragma unroll
        for (int ni = 0; ni < 2; ni++){
          short8 vf = *(const short8*)&vT[hh][ni * 16 + colb][kc2 * 32 + kb];
          #pragma unroll
          for (int mi = 0; mi < 2; mi++)
            oacc[mi][ni] = mfma16(pf[mi], vf, oacc[mi][ni]);
        }
      }
      #pragma unroll
      for (int mi = 0; mi < 2; mi++)
        #pragma unroll
        for (int ni = 0; ni < 2; ni++)
          #pragma unroll
          for (int r = 0; r < 4; r++){
            int rm = mh * 32 + mi * 16 + ((lane >> 4) << 2) + r;
            int c = head * HD + ni * 16 + colb;
            attnout[((size_t)wi * 64 + rm) * DIM + c] = __float2bfloat16(oacc[mi][ni][r]);
          }
    }
    __syncthreads();
  }
}

// ---- proj: M=64 x N=384(full) x K=384 GEMM + LN1 + unshift + residual ----
__global__ __launch_bounds__(256, 2) void k_proj(
    const __hip_bfloat16* __restrict__ attnout,
    const __hip_bfloat16* __restrict__ projw,
    const float* __restrict__ projb,
    const float* __restrict__ x,
    const float* __restrict__ g1, const float* __restrict__ b1v,
    __hip_bfloat16* __restrict__ yout)
{
  __shared__ __attribute__((aligned(16))) char stage[2][28672];  // 28 slots
  __shared__ float red1[64][4], red2[64][4];
  const int tid = threadIdx.x, lane = tid & 63, wid = tid >> 6;
  const int colb = lane & 15, hi = lane >> 4;
  const size_t row0 = (size_t)blockIdx.x * 64;

  auto stg = [&](int buf, int kc){
    #pragma unroll
    for (int j = 0; j < 7; j++){
      int s = wid * 7 + j;
      const __hip_bfloat16* src;
      if (s < 4) src = attnout + (row0 + s * 16 + colb) * DIM + kc * 32 + hi * 8;
      else       src = projw + (size_t)((s - 4) * 16 + colb) * DIM + kc * 32 + hi * 8;
      gload16(src, &stage[buf][s * 1024]);
    }
  };

  f32x4 acc[4][6];
  #pragma unroll
  for (int mi = 0; mi < 4; mi++)
    #pragma unroll
    for (int ni = 0; ni < 6; ni++) acc[mi][ni] = (f32x4)(0.f);

  int buf = 0;
  stg(0, 0);
  __syncthreads();
  for (int kc = 0; kc < 12; kc++){
    if (kc < 11) stg(buf ^ 1, kc + 1);
    short8 a[4], b[6];
    #pragma unroll
    for (int mi = 0; mi < 4; mi++)
      a[mi] = *(const short8*)&stage[buf][mi * 1024 + lane * 16];
    #pragma unroll
    for (int ni = 0; ni < 6; ni++)
      b[ni] = *(const short8*)&stage[buf][(4 + wid * 6 + ni) * 1024 + lane * 16];
    #pragma unroll
    for (int mi = 0; mi < 4; mi++)
      #pragma unroll
      for (int ni = 0; ni < 6; ni++)
        acc[mi][ni] = mfma16(a[mi], b[ni], acc[mi][ni]);
    __syncthreads();
    buf ^= 1;
  }

  float s1[4][4], s2[4][4];
  #pragma unroll
  for (int mi = 0; mi < 4; mi++)
    #pragma unroll
    for (int rr = 0; rr < 4; rr++){ s1[mi][rr] = 0.f; s2[mi][rr] = 0.f; }
  #pragma unroll
  for (int ni = 0; ni < 6; ni++){
    float pb = projb[wid * 96 + ni * 16 + colb];
    #pragma unroll
    for (int mi = 0; mi < 4; mi++)
      #pragma unroll
      for (int rr = 0; rr < 4; rr++){
        float v = acc[mi][ni][rr] + pb;
        acc[mi][ni][rr] = v;
        s1[mi][rr] += v; s2[mi][rr] += v * v;
      }
  }
  #pragma unroll
  for (int mi = 0; mi < 4; mi++)
    #pragma unroll
    for (int rr = 0; rr < 4; rr++){
      float a = wsum16(s1[mi][rr]);
      float b = wsum16(s2[mi][rr]);
      if (colb == 0){
        int row = mi * 16 + hi * 4 + rr;
        red1[row][wid] = a; red2[row][wid] = b;
      }
    }
  __syncthreads();

  #pragma unroll
  for (int mi = 0; mi < 4; mi++)
    #pragma unroll
    for (int rr = 0; rr < 4; rr++){
      int row = mi * 16 + hi * 4 + rr;
      float t1 = red1[row][0] + red1[row][1] + red1[row][2] + red1[row][3];
      float t2 = red2[row][0] + red2[row][1] + red2[row][2] + red2[row][3];
      float mean = t1 * (1.f / 384.f);
      float var  = t2 * (1.f / 384.f) - mean * mean;
      float inv  = rsqrtf(var + 1e-5f);
      size_t arow = row0 + row;
      int wi2 = (int)(arow >> 6), t = (int)(arow & 63);
      int bb = wi2 >> 6, wh = (wi2 >> 3) & 7, ww = wi2 & 7;
      int rr2 = t >> 3, cc = t & 7;
      int h = (wh * 8 + rr2 + 4) & 63, w = (ww * 8 + cc + 4) & 63;
      size_t gpos = ((size_t)bb << 12) + (h << 6) + w;
      const float* xp = x + gpos * DIM;
      __hip_bfloat16* yp = yout + gpos * DIM;
      #pragma unroll
      for (int ni = 0; ni < 6; ni++){
        int c = wid * 96 + ni * 16 + colb;
        float ln = (acc[mi][ni][rr] - mean) * inv * g1[c] + b1v[c];
        yp[c] = __float2bfloat16(xp[c] + ln);
      }
    }
}

// ---- fc1: 128x128 tile GEMM (K=384) + bias + GELU -> h bf16 --------------
__global__ __launch_bounds__(256, 3) void k_fc1(
    const __hip_bfloat16* __restrict__ y,      // [Mchunk][384]
    const __hip_bfloat16* __restrict__ fc1w,   // [1536][384]
    const float* __restrict__ fc1b,
    __hip_bfloat16* __restrict__ h)            // [Mchunk][1536]
{
  __shared__ __attribute__((aligned(16))) char stage[2][16384];  // 16 slots
  const int tid = threadIdx.x, lane = tid & 63, wid = tid >> 6;
  const int colb = lane & 15, hi = lane >> 4;
  const int mt = blockIdx.x / 12, nt = blockIdx.x % 12;
  const size_t row0 = (size_t)mt * 128;
  const int col0 = nt * 128;
  const int wm = wid >> 1, wn = wid & 1;

  auto stg = [&](int buf, int kc){
    #pragma unroll
    for (int j = 0; j < 4; j++){
      int s = wid * 4 + j;
      const __hip_bfloat16* src;
      if (s < 8) src = y + (row0 + s * 16 + colb) * DIM + kc * 32 + hi * 8;
      else       src = fc1w + (size_t)(col0 + (s - 8) * 16 + colb) * DIM + kc * 32 + hi * 8;
      gload16(src, &stage[buf][s * 1024]);
    }
  };

  f32x4 acc[4][4];
  #pragma unroll
  for (int mi = 0; mi < 4; mi++)
    #pragma unroll
    for (int ni = 0; ni < 4; ni++) acc[mi][ni] = (f32x4)(0.f);

  int buf = 0;
  stg(0, 0);
  __syncthreads();
  for (int kc = 0; kc < 12; kc++){
    if (kc < 11) stg(buf ^ 1, kc + 1);
    short8 a[4], b[4];
    #pragma unroll
    for (int mi = 0; mi < 4; mi++)
      a[mi] = *(const short8*)&stage[buf][(wm * 4 + mi) * 1024 + lane * 16];
    #pragma unroll
    for (int ni = 0; ni < 4; ni++)
      b[ni] = *(const short8*)&stage[buf][(8 + wn * 4 + ni) * 1024 + lane * 16];
    #pragma unroll
    for (int mi = 0; mi < 4; mi++)
      #pragma unroll
      for (int ni = 0; ni < 4; ni++)
        acc[mi][ni] = mfma16(a[mi], b[ni], acc[mi][ni]);
    __syncthreads();
    buf ^= 1;
  }

  // epilogue: bias + GELU -> h
  #pragma unroll
  for (int ni = 0; ni < 4; ni++){
    int c = col0 + wn * 64 + ni * 16 + colb;
    float fb = fc1b[c];
    #pragma unroll
    for (int mi = 0; mi < 4; mi++){
      size_t rbase = row0 + wm * 64 + mi * 16 + hi * 4;
      #pragma unroll
      for (int rr = 0; rr < 4; rr++){
        float v = acc[mi][ni][rr] + fb;
        float u = v * (1.0f + 0.044715f * v * v);
        float gl = v / (1.0f + __expf(-1.5957691216f * u));
        h[(rbase + rr) * 1536 + c] = __float2bfloat16(gl);
      }
    }
  }
}

// ---- fc2: M=64 x N=384(full) x K=1536 GEMM + LN2 + residual -> out f32 ---
__global__ __launch_bounds__(256, 2) void k_fc2(
    const __hip_bfloat16* __restrict__ h,      // [Mchunk][1536]
    const __hip_bfloat16* __restrict__ fc2w,   // [384][1536]
    const float* __restrict__ fc2b,
    const __hip_bfloat16* __restrict__ y,      // residual
    const float* __restrict__ g2, const float* __restrict__ b2v,
    float* __restrict__ out)
{
  __shared__ __attribute__((aligned(16))) char stage[2][28672];  // 28 slots
  __shared__ float red1[64][4], red2[64][4];
  const int tid = threadIdx.x, lane = tid & 63, wid = tid >> 6;
  const int colb = lane & 15, hi = lane >> 4;
  const size_t row0 = (size_t)blockIdx.x * 64;

  auto stg = [&](int buf, int kc){
    #pragma unroll
    for (int j = 0; j < 7; j++){
      int s = wid * 7 + j;
      const __hip_bfloat16* src;
      if (s < 4) src = h + (row0 + s * 16 + colb) * 1536 + kc * 32 + hi * 8;
      else       src = fc2w + (size_t)((s - 4) * 16 + colb) * 1536 + kc * 32 + hi * 8;
      gload16(src, &stage[buf][s * 1024]);
    }
  };

  f32x4 acc[4][6];
  #pragma unroll
  for (int mi = 0; mi < 4; mi++)
    #pragma unroll
    for (int ni = 0; ni < 6; ni++) acc[mi][ni] = (f32x4)(0.f);

  int buf = 0;
  stg(0, 0);
  __syncthreads();
  for (int kc = 0; kc < 48; kc++){
    if (kc < 47) stg(buf ^ 1, kc + 1);
    short8 a[4], b[6];
    #pragma unroll
    for (int mi = 0; mi < 4; mi++)
      a[mi] = *(const short8*)&stage[buf][mi * 1024 + lane * 16];
    #pragma unroll
    for (int ni = 0; ni < 6; ni++)
      b[ni] = *(const short8*)&stage[buf][(4 + wid * 6 + ni) * 1024 + lane * 16];
    #pragma unroll
    for (int mi = 0; mi < 4; mi++)
      #pragma unroll
      for (int ni = 0; ni < 6; ni++)
        acc[mi][ni] = mfma16(a[mi], b[ni], acc[mi][ni]);
    __syncthreads();
    buf ^= 1;
  }

  float s1[4][4], s2[4][4];
  #pragma unroll
  for (int mi = 0; mi < 4; mi++)
    #pragma unroll
    for (int rr = 0; rr < 4; rr++){ s1[mi][rr] = 0.f; s2[mi][rr] = 0.f; }
  #pragma unroll
  for (int ni = 0; ni < 6; ni++){
    float fb = fc2b[wid * 96 + ni * 16 + colb];
    #pragma unroll
    for (int mi = 0; mi < 4; mi++)
      #pragma unroll
      for (int rr = 0; rr < 4; rr++){
        float v = acc[mi][ni][rr] + fb;
        acc[mi][ni][rr] = v;
        s1[mi][rr] += v; s2[mi][rr] += v * v;
      }
  }
  #pragma unroll
  for (int mi = 0; mi < 4; mi++)
    #pragma unroll
    for (int rr = 0; rr < 4; rr++){
      float a = wsum16(s1[mi][rr]);
      float b = wsum16(s2[mi][rr]);
      if (colb == 0){
        int row = mi * 16 + hi * 4 + rr;
        red1[row][wid] = a; red2[row][wid] = b;
      }
    }
  __syncthreads();

  #pragma unroll
  for (int mi = 0; mi < 4; mi++)
    #pragma unroll
    for (int rr = 0; rr < 4; rr++){
      int row = mi * 16 + hi * 4 + rr;
      float t1 = red1[row][0] + red1[row][1] + red1[row][2] + red1[row][3];
      float t2 = red2[row][0] + red2[row][1] + red2[row][2] + red2[row][3];
      float mean = t1 * (1.f / 384.f);
      float var  = t2 * (1.f / 384.f) - mean * mean;
      float inv  = rsqrtf(var + 1e-5f);
      size_t grow = row0 + row;
      const __hip_bfloat16* yp = y + grow * DIM;
      float* op = out + grow * DIM;
      #pragma unroll
      for (int ni = 0; ni < 6; ni++){
        int c = wid * 96 + ni * 16 + colb;
        float ln = (acc[mi][ni][rr] - mean) * inv * g2[c] + b2v[c];
        op[c] = __bfloat162float(yp[c]) + ln;
      }
    }
}

extern "C" void kernel_launch(void* const* d_in, const int* in_sizes, int n_in,
                              void* d_out, int out_size, void* d_ws, size_t ws_size,
                              hipStream_t stream)
{
  (void)in_sizes; (void)n_in; (void)out_size; (void)ws_size;
  const float* x    = (const float*)d_in[0];
  const float* qkvw_f = (const float*)d_in[3];
  const float* qkvb = (const float*)d_in[4];
  const float* lsc  = (const float*)d_in[5];
  const float* cw1  = (const float*)d_in[6];
  const float* cb1  = (const float*)d_in[7];
  const float* cw2  = (const float*)d_in[8];
  const float* pw   = (const float*)d_in[9];
  const float* pb   = (const float*)d_in[10];
  const float* g1   = (const float*)d_in[11];
  const float* b1   = (const float*)d_in[12];
  const float* g2   = (const float*)d_in[13];
  const float* b2   = (const float*)d_in[14];
  const float* f1w  = (const float*)d_in[15];
  const float* f1b  = (const float*)d_in[16];
  const float* f2w  = (const float*)d_in[17];
  const float* f2b  = (const float*)d_in[18];

  char* ws = (char*)d_ws;
  size_t off = 0;
  auto alloc = [&](size_t bytes) -> char* {
    char* p = ws + off;
    off += (bytes + 255) & ~(size_t)255;
    return p;
  };
  __hip_bfloat16* qkvw_h  = (__hip_bfloat16*)alloc((size_t)1152 * 384 * 2);
  __hip_bfloat16* projw_h = (__hip_bfloat16*)alloc((size_t)384 * 384 * 2);
  __hip_bfloat16* fc1w_h  = (__hip_bfloat16*)alloc((size_t)1536 * 384 * 2);
  __hip_bfloat16* fc2w_h  = (__hip_bfloat16*)alloc((size_t)384 * 1536 * 2);
  float* scalev = (float*)alloc(NH * 4);
  float* hbias  = (float*)alloc(225 * NH * 4);
  float* bias16 = (float*)alloc((size_t)NH * 64 * 64 * 4);
  __hip_bfloat16* attnout = (__hip_bfloat16*)alloc((size_t)2048 * 64 * 384 * 2);
  __hip_bfloat16* yb      = (__hip_bfloat16*)alloc((size_t)131072 * 384 * 2);
  // h (100.66 MB per 32768-row chunk) overlays attnout (dead after k_proj)
  __hip_bfloat16* hbuf    = attnout;

  k_f32_to_bf16<<<512, 256, 0, stream>>>(qkvw_f, qkvw_h, 1152 * 384);
  k_f32_to_bf16<<<256, 256, 0, stream>>>(pw, projw_h, 384 * 384);
  k_f32_to_bf16<<<512, 256, 0, stream>>>(f1w, fc1w_h, 1536 * 384);
  k_f32_to_bf16<<<512, 256, 0, stream>>>(f2w, fc2w_h, 384 * 1536);
  k_cpb<<<225, 256, 0, stream>>>(cw1, cb1, cw2, hbias);
  k_bias16<<<192, 256, 0, stream>>>(hbias, lsc, bias16, scalev);
  k_attn<<<2048, 256, 0, stream>>>(x, qkvw_h, qkvb, scalev, bias16, attnout);
  k_proj<<<2048, 256, 0, stream>>>(attnout, projw_h, pb, x, g1, b1, yb);

  for (int c = 0; c < 4; c++){
    size_t ro = (size_t)c * 32768;
    k_fc1<<<3072, 256, 0, stream>>>(yb + ro * DIM, fc1w_h, f1b, hbuf);
    k_fc2<<<512, 256, 0, stream>>>(hbuf, fc2w_h, f2b, yb + ro * DIM,
                                   g2, b2, (float*)d_out + ro * DIM);
  }
}